// Round 3
// baseline (350.062 us; speedup 1.0000x reference)
//
#include <hip/hip_runtime.h>
#include <hip/hip_bf16.h>
#include <stdint.h>

// ---------------------------------------------------------------------------
// SelfAttention block: out = (attn(rope(rms(xWq)), rope(rms(xWk)), xWv)) Wo
// B=2, N=2048, D=2048, H=16, HD=128.  All GEMMs + attention in bf16 MFMA.
// ---------------------------------------------------------------------------

typedef __bf16 bf16;
typedef __bf16 bf16x8 __attribute__((ext_vector_type(8)));
typedef __bf16 bf16x4 __attribute__((ext_vector_type(4)));
typedef float  f32x4  __attribute__((ext_vector_type(4)));

#define MTOT   4096   // B*N token rows
#define DMODEL 2048
#define NSEQ   2048
#define NHEAD  16
#define HDIM   128

static __device__ __forceinline__ void async_ld16(const void* g, void* l) {
  void* gnc = const_cast<void*>(g);
  __builtin_amdgcn_global_load_lds((__attribute__((address_space(1))) void*)gnc,
                                   (__attribute__((address_space(3))) void*)l,
                                   16, 0, 0);
}

// ---------------------------------------------------------------------------
// Fused f32 -> bf16 converts: x, wq, wk, wv in one launch.
// ---------------------------------------------------------------------------
#define XG (MTOT * DMODEL / 8)      // 1048576 groups of 8
#define WG (DMODEL * DMODEL / 8)    // 524288

__global__ __launch_bounds__(256) void k_cvt4(
    const float* __restrict__ x, const float* __restrict__ wq,
    const float* __restrict__ wk, const float* __restrict__ wv,
    bf16* __restrict__ xb, bf16* __restrict__ wqb, bf16* __restrict__ wkb,
    bf16* __restrict__ wvb) {
  int stride = gridDim.x * blockDim.x;
  for (int i = blockIdx.x * blockDim.x + threadIdx.x; i < XG + 3 * WG;
       i += stride) {
    const float* src;
    bf16* dst;
    int off;
    if (i < XG) { src = x; dst = xb; off = i; }
    else if (i < XG + WG) { src = wq; dst = wqb; off = i - XG; }
    else if (i < XG + 2 * WG) { src = wk; dst = wkb; off = i - XG - WG; }
    else { src = wv; dst = wvb; off = i - XG - 2 * WG; }
    const float4* p = (const float4*)(src) + 2 * (size_t)off;
    float4 a = p[0], b = p[1];
    bf16x8 o;
    o[0] = (bf16)a.x; o[1] = (bf16)a.y; o[2] = (bf16)a.z; o[3] = (bf16)a.w;
    o[4] = (bf16)b.x; o[5] = (bf16)b.y; o[6] = (bf16)b.z; o[7] = (bf16)b.w;
    *((bf16x8*)(dst) + off) = o;
  }
}

__global__ __launch_bounds__(256) void k_cvt(const float* __restrict__ in,
                                             bf16* __restrict__ out, int n8) {
  int stride = gridDim.x * blockDim.x;
  for (int i = blockIdx.x * blockDim.x + threadIdx.x; i < n8; i += stride) {
    const float4* p = (const float4*)(in) + 2 * (size_t)i;
    float4 a = p[0], b = p[1];
    bf16x8 o;
    o[0] = (bf16)a.x; o[1] = (bf16)a.y; o[2] = (bf16)a.z; o[3] = (bf16)a.w;
    o[4] = (bf16)b.x; o[5] = (bf16)b.y; o[6] = (bf16)b.z; o[7] = (bf16)b.w;
    *((bf16x8*)(out) + i) = o;
  }
}

// ---------------------------------------------------------------------------
// GEMM v2: C[m][n] = sum_k A[m][k]*W[n][k] + bias[n].  128x256 tile, BK=64,
// 8 waves (2M x 4N), wave-tile 64x64 (4x4 16x16x32 frags). Deep pipeline:
// stage burst for kt+1 at iter start, s_waitcnt vmcnt(6) keeps next tile's
// loads in flight across the whole compute; 2 barriers / K-tile.
// LDS 96KB dynamic: sa[2][128*64] + sb[2][256*64], XOR-swizzled chunks.
// OUTMODE 0: bf16 row-major; 1: bf16 transposed (vt[b][n][s]); 2: f32.
// ---------------------------------------------------------------------------
template <int OUTMODE>
static __device__ __forceinline__ void gemm256_body(
    const bf16* __restrict__ A, const bf16* __restrict__ W,
    const float* __restrict__ bias, void* __restrict__ outp, int m0, int n0) {
  extern __shared__ __align__(16) bf16 dynls[];
  bf16* sa = dynls;                    // [2][128*64]
  bf16* sb = dynls + 2 * 128 * 64;     // [2][256*64]

  const int tid = threadIdx.x;
  const int lane = tid & 63, w = tid >> 6;
  const int wm = w >> 2, wn = w & 3;
  const int g = lane >> 4, r0 = lane & 15;

  f32x4 acc[4][4];
  const f32x4 vzero = {0.f, 0.f, 0.f, 0.f};
#pragma unroll
  for (int i = 0; i < 4; ++i)
#pragma unroll
    for (int j = 0; j < 4; ++j) acc[i][j] = vzero;

  const bf16* Abase = A + (size_t)m0 * DMODEL;
  const bf16* Wbase = W + (size_t)n0 * DMODEL;

  auto stage = [&](int kt, int buf) {
    const bf16* asrc = Abase + kt * 64;
    const bf16* bsrc = Wbase + kt * 64;
    bf16* sA = sa + buf * (128 * 64);
    bf16* sB = sb + buf * (256 * 64);
#pragma unroll
    for (int p = 0; p < 2; ++p) {      // A: 128x64 = 1024 chunks
      int ch = tid + p * 512;
      int row = ch >> 3, cs = ch & 7, c = cs ^ (row & 7);
      async_ld16(asrc + (size_t)row * DMODEL + c * 8, sA + ch * 8);
    }
#pragma unroll
    for (int p = 0; p < 4; ++p) {      // B: 256x64 = 2048 chunks
      int ch = tid + p * 512;
      int row = ch >> 3, cs = ch & 7, c = cs ^ (row & 7);
      async_ld16(bsrc + (size_t)row * DMODEL + c * 8, sB + ch * 8);
    }
  };

  const int NT = DMODEL / 64;  // 32
  stage(0, 0);
  for (int kt = 0; kt < NT; ++kt) {
    const int cb = kt & 1;
    __syncthreads();  // (A) all reads of buf[cb^1] from iter kt-1 complete
    if (kt + 1 < NT) {
      stage(kt + 1, cb ^ 1);
      asm volatile("s_waitcnt vmcnt(6)" ::: "memory");  // kt landed; kt+1 in flight
    } else {
      asm volatile("s_waitcnt vmcnt(0)" ::: "memory");
    }
    __syncthreads();  // (B) buf[cb] visible to all waves
    const bf16* sA = sa + cb * (128 * 64);
    const bf16* sB = sb + cb * (256 * 64);
#pragma unroll
    for (int q = 0; q < 4; ++q) {  // quadrant (mq,nq) of wave's 64x64 tile
      const int mq = q >> 1, nq = q & 1;
      bf16x8 af[2][2], bfr[2][2];
#pragma unroll
      for (int d = 0; d < 2; ++d) {
        int ra = wm * 64 + (2 * mq + d) * 16 + r0;
        int rb = wn * 64 + (2 * nq + d) * 16 + r0;
#pragma unroll
        for (int ks = 0; ks < 2; ++ks) {
          int cc = ks * 4 + g;
          af[d][ks] = *(const bf16x8*)(sA + ra * 64 + ((cc ^ (ra & 7)) << 3));
          bfr[d][ks] = *(const bf16x8*)(sB + rb * 64 + ((cc ^ (rb & 7)) << 3));
        }
      }
      __builtin_amdgcn_s_setprio(1);
#pragma unroll
      for (int di = 0; di < 2; ++di)
#pragma unroll
        for (int dj = 0; dj < 2; ++dj)
#pragma unroll
          for (int ks = 0; ks < 2; ++ks)
            acc[2 * mq + di][2 * nq + dj] = __builtin_amdgcn_mfma_f32_16x16x32_bf16(
                af[di][ks], bfr[dj][ks], acc[2 * mq + di][2 * nq + dj], 0, 0, 0);
      __builtin_amdgcn_s_setprio(0);
      __builtin_amdgcn_sched_barrier(0);
    }
  }

  // epilogue: C frag layout col = lane&15, row = (lane>>4)*4 + r
#pragma unroll
  for (int i = 0; i < 4; ++i) {
#pragma unroll
    for (int j = 0; j < 4; ++j) {
      int mb = m0 + wm * 64 + i * 16 + g * 4;
      int n = n0 + wn * 64 + j * 16 + r0;
      float bn = bias[n];
      if (OUTMODE == 0) {
        bf16* o = (bf16*)outp;
#pragma unroll
        for (int r = 0; r < 4; ++r)
          o[(size_t)(mb + r) * DMODEL + n] = (bf16)(acc[i][j][r] + bn);
      } else if (OUTMODE == 2) {
        float* o = (float*)outp;
#pragma unroll
        for (int r = 0; r < 4; ++r)
          o[(size_t)(mb + r) * DMODEL + n] = acc[i][j][r] + bn;
      } else {
        bf16* o = (bf16*)outp;
        int bb = mb >> 11, s = mb & (NSEQ - 1);
        bf16x4 pk;
#pragma unroll
        for (int r = 0; r < 4; ++r) pk[r] = (bf16)(acc[i][j][r] + bn);
        *(bf16x4*)(o + (size_t)(bb * DMODEL + n) * NSEQ + s) = pk;
      }
    }
  }
}

__global__ __launch_bounds__(512, 2) void k_gemm_qkv(
    const bf16* __restrict__ xb, const bf16* __restrict__ wq,
    const bf16* __restrict__ wk, const bf16* __restrict__ wv,
    const float* __restrict__ bq, const float* __restrict__ bk,
    const float* __restrict__ bv, bf16* __restrict__ q, bf16* __restrict__ k,
    bf16* __restrict__ vt) {
  int nb = blockIdx.x;           // 24 = 3 sections x 8 n-blocks
  int m0 = blockIdx.y * 128;
  int sec = nb >> 3;
  int n0 = (nb & 7) * 256;
  if (sec == 0)
    gemm256_body<0>(xb, wq, bq, q, m0, n0);
  else if (sec == 1)
    gemm256_body<0>(xb, wk, bk, k, m0, n0);
  else
    gemm256_body<1>(xb, wv, bv, vt, m0, n0);
}

__global__ __launch_bounds__(512, 2) void k_gemm_out(
    const bf16* __restrict__ ab, const bf16* __restrict__ wo,
    const float* __restrict__ bo, float* __restrict__ out) {
  gemm256_body<2>(ab, wo, bo, out, blockIdx.y * 128, blockIdx.x * 256);
}

// ---------------------------------------------------------------------------
// Fused RMSNorm + RoPE (+ fold 1/sqrt(HD) into q so attn skips the scale).
// ---------------------------------------------------------------------------
__global__ __launch_bounds__(256) void k_norm_rope(
    bf16* __restrict__ q, bf16* __restrict__ kk, const float* __restrict__ gq,
    const float* __restrict__ gk, const float* __restrict__ freqs) {
  int bidx = blockIdx.x;
  bf16* buf = (bidx < MTOT) ? q : kk;
  const float* gw = (bidx < MTOT) ? gq : gk;
  float qs = (bidx < MTOT) ? 0.08838834764831845f : 1.0f;  // 1/sqrt(128)
  int row = bidx & (MTOT - 1);
  int s = row & (NSEQ - 1);
  int tid = threadIdx.x;
  int i0 = tid * 8;
  bf16* ptr = buf + (size_t)row * DMODEL + i0;
  bf16x8 v = *(const bf16x8*)ptr;
  float x[8];
  float ssq = 0.f;
#pragma unroll
  for (int j = 0; j < 8; ++j) {
    x[j] = (float)v[j];
    ssq += x[j] * x[j];
  }
#pragma unroll
  for (int off = 1; off < 64; off <<= 1) ssq += __shfl_xor(ssq, off);
  __shared__ float part[4];
  if ((tid & 63) == 0) part[tid >> 6] = ssq;
  __syncthreads();
  float tot = part[0] + part[1] + part[2] + part[3];
  float sc = rsqrtf(tot * (1.f / DMODEL) + 1e-6f) * qs;
  float4 g0 = *(const float4*)(gw + i0);
  float4 g1 = *(const float4*)(gw + i0 + 4);
  float y[8];
  y[0] = x[0] * sc * g0.x; y[1] = x[1] * sc * g0.y;
  y[2] = x[2] * sc * g0.z; y[3] = x[3] * sc * g0.w;
  y[4] = x[4] * sc * g1.x; y[5] = x[5] * sc * g1.y;
  y[6] = x[6] * sc * g1.z; y[7] = x[7] * sc * g1.w;
  int dl = i0 & (HDIM - 1);
  const float* fp = freqs + (size_t)s * HDIM + dl;
  float4 f0 = *(const float4*)fp;
  float4 f1 = *(const float4*)(fp + 4);
  bf16x8 out;
  out[0] = (bf16)(y[0] * f0.x - y[1] * f0.y);
  out[1] = (bf16)(y[0] * f0.y + y[1] * f0.x);
  out[2] = (bf16)(y[2] * f0.z - y[3] * f0.w);
  out[3] = (bf16)(y[2] * f0.w + y[3] * f0.z);
  out[4] = (bf16)(y[4] * f1.x - y[5] * f1.y);
  out[5] = (bf16)(y[4] * f1.y + y[5] * f1.x);
  out[6] = (bf16)(y[6] * f1.z - y[7] * f1.w);
  out[7] = (bf16)(y[6] * f1.w + y[7] * f1.z);
  *(bf16x8*)ptr = out;
}

// ---------------------------------------------------------------------------
// Flash attention v2 (unchanged from R2): swapped QK^T, in-register softmax,
// P via cvt_pk + shfl, K/V double-buffer prefetch.
// ---------------------------------------------------------------------------
__global__ __launch_bounds__(512, 4) void k_attn(const bf16* __restrict__ q,
                                                 const bf16* __restrict__ k,
                                                 const bf16* __restrict__ vt,
                                                 bf16* __restrict__ o) {
  __shared__ __align__(16) bf16 sk[2][64 * 128];
  __shared__ __align__(16) bf16 sv[2][128 * 64];
  const int bid = blockIdx.x;
  const int idx = bid >> 3;
  const int bh = (bid & 7) * 4 + (idx >> 4);  // 4 bh per XCD
  const int qt = idx & 15;
  const int bb = bh >> 4, h = bh & 15;
  const int tid = threadIdx.x;
  const int lane = tid & 63, w = tid >> 6;
  const int g = lane >> 4, r0 = lane & 15;

  bf16x8 qf[4];
  {
    const bf16* qbase =
        q + (size_t)(bb * NSEQ + qt * 128 + w * 16 + r0) * DMODEL + h * HDIM;
#pragma unroll
    for (int ds = 0; ds < 4; ++ds)
      qf[ds] = *(const bf16x8*)(qbase + ds * 32 + g * 8);
  }
  f32x4 oacc[8];
  const f32x4 vzero = {0.f, 0.f, 0.f, 0.f};
#pragma unroll
  for (int dt = 0; dt < 8; ++dt) oacc[dt] = vzero;
  float m = -3.0e38f, l = 0.f;

  const bf16* kbase = k + (size_t)(bb * NSEQ) * DMODEL + h * HDIM;
  const bf16* vbase = vt + (size_t)(bb * DMODEL + h * HDIM) * NSEQ;

  const int s0lane = ((lane & 16) << 1) | r0;
  const int s1lane = s0lane | 16;
  const bool hi5 = (lane & 32) != 0;

  auto stage = [&](int t, int buf) {
    int k0 = t * 64;
#pragma unroll
    for (int p = 0; p < 2; ++p) {
      int ch = tid + p * 512;
      int row = ch >> 4, cs = ch & 15;
      int c = cs ^ (row & 7);
      async_ld16(kbase + (size_t)(k0 + row) * DMODEL + c * 8, &sk[buf][ch * 8]);
    }
#pragma unroll
    for (int p = 0; p < 2; ++p) {
      int ch = tid + p * 512;
      int row = ch >> 3, cs = ch & 7;
      int c = cs ^ (row & 7);
      async_ld16(vbase + (size_t)row * NSEQ + k0 + c * 8, &sv[buf][ch * 8]);
    }
  };

  stage(0, 0);
  for (int t = 0; t < NSEQ / 64; ++t) {
    const int cur = t & 1;
    asm volatile("s_waitcnt vmcnt(0)" ::: "memory");
    __syncthreads();
    if (t + 1 < NSEQ / 64) stage(t + 1, cur ^ 1);

    f32x4 sacc[4];
#pragma unroll
    for (int kkt = 0; kkt < 4; ++kkt) sacc[kkt] = vzero;
#pragma unroll
    for (int kkt = 0; kkt < 4; ++kkt) {
      int rk = kkt * 16 + r0;
#pragma unroll
      for (int ds = 0; ds < 4; ++ds) {
        int c = ds * 4 + g;
        bf16x8 kf = *(const bf16x8*)(&sk[cur][rk * 128 + ((c ^ (rk & 7)) << 3)]);
        sacc[kkt] =
            __builtin_amdgcn_mfma_f32_16x16x32_bf16(kf, qf[ds], sacc[kkt], 0, 0, 0);
      }
    }

    float pm = sacc[0][0];
#pragma unroll
    for (int kkt = 0; kkt < 4; ++kkt)
#pragma unroll
      for (int r = 0; r < 4; ++r) pm = fmaxf(pm, sacc[kkt][r]);
    pm = fmaxf(pm, __shfl_xor(pm, 16));
    pm = fmaxf(pm, __shfl_xor(pm, 32));
    const int need = __any(pm > m);
    const float mu = need ? fmaxf(m, pm) : m;

    uint32_t W[4][2];
    float rs = 0.f;
#pragma unroll
    for (int kkt = 0; kkt < 4; ++kkt) {
      float p0 = __expf(sacc[kkt][0] - mu);
      float p1 = __expf(sacc[kkt][1] - mu);
      float p2 = __expf(sacc[kkt][2] - mu);
      float p3 = __expf(sacc[kkt][3] - mu);
      rs += (p0 + p1) + (p2 + p3);
      asm("v_cvt_pk_bf16_f32 %0, %1, %2" : "=v"(W[kkt][0]) : "v"(p0), "v"(p1));
      asm("v_cvt_pk_bf16_f32 %0, %1, %2" : "=v"(W[kkt][1]) : "v"(p2), "v"(p3));
    }
    rs += __shfl_xor(rs, 16);
    rs += __shfl_xor(rs, 32);

    if (need) {
      float alpha = __expf(m - mu);
      m = mu;
      l = l * alpha + rs;
      float a4[4];
#pragma unroll
      for (int r = 0; r < 4; ++r)
        a4[r] = __shfl(alpha, (lane & 48) | (g * 4 + r));
#pragma unroll
      for (int dt = 0; dt < 8; ++dt)
#pragma unroll
        for (int r = 0; r < 4; ++r) oacc[dt][r] *= a4[r];
    } else {
      l += rs;
    }

#pragma unroll
    for (int ks = 0; ks < 2; ++ks) {
      union { uint32_t u[4]; bf16x8 v; } pa;
#pragma unroll
      for (int ww = 0; ww < 4; ++ww) {
        int src = (ww < 2) ? s0lane : s1lane;
        int lo = __shfl((int)W[2 * ks][ww & 1], src);
        int hv = __shfl((int)W[2 * ks + 1][ww & 1], src);
        pa.u[ww] = hi5 ? (uint32_t)hv : (uint32_t)lo;
      }
#pragma unroll
      for (int dt = 0; dt < 8; ++dt) {
        int rv = dt * 16 + r0;
        int c = ks * 4 + g;
        bf16x8 vf = *(const bf16x8*)(&sv[cur][rv * 64 + ((c ^ (rv & 7)) << 3)]);
        oacc[dt] =
            __builtin_amdgcn_mfma_f32_16x16x32_bf16(pa.v, vf, oacc[dt], 0, 0, 0);
      }
    }
  }

  float rl[4];
#pragma unroll
  for (int r = 0; r < 4; ++r) {
    float lr = __shfl(l, (lane & 48) | (g * 4 + r));
    rl[r] = 1.f / lr;
  }
  bf16* obase =
      o + (size_t)(bb * NSEQ + qt * 128 + w * 16 + g * 4) * DMODEL + h * HDIM;
#pragma unroll
  for (int dt = 0; dt < 8; ++dt)
#pragma unroll
    for (int r = 0; r < 4; ++r)
      obase[(size_t)r * DMODEL + dt * 16 + r0] = (bf16)(oacc[dt][r] * rl[r]);
}

// ---------------------------------------------------------------------------
extern "C" void kernel_launch(void* const* d_in, const int* in_sizes, int n_in,
                              void* d_out, int out_size, void* d_ws,
                              size_t ws_size, hipStream_t stream) {
  (void)in_sizes; (void)n_in; (void)out_size; (void)ws_size;
  const float* x = (const float*)d_in[0];
  const float* freqs = (const float*)d_in[1];
  const float* wq = (const float*)d_in[2];
  const float* bq = (const float*)d_in[3];
  const float* wk = (const float*)d_in[4];
  const float* bk = (const float*)d_in[5];
  const float* wv = (const float*)d_in[6];
  const float* bv = (const float*)d_in[7];
  const float* wo = (const float*)d_in[8];
  const float* bo = (const float*)d_in[9];
  const float* gq = (const float*)d_in[10];
  const float* gk = (const float*)d_in[11];

  char* ws = (char*)d_ws;
  const size_t SZ_TOK = (size_t)MTOT * DMODEL * sizeof(bf16);
  const size_t SZ_W = (size_t)DMODEL * DMODEL * sizeof(bf16);
  bf16* xb = (bf16*)ws;                 // attn-out after qkv
  bf16* qb = (bf16*)(ws + SZ_TOK);
  bf16* kb = (bf16*)(ws + 2 * SZ_TOK);
  bf16* vtb = (bf16*)(ws + 3 * SZ_TOK);
  bf16* wqb = (bf16*)(ws + 4 * SZ_TOK);  // wo-bf16 after qkv
  bf16* wkb = (bf16*)(ws + 4 * SZ_TOK + SZ_W);
  bf16* wvb = (bf16*)(ws + 4 * SZ_TOK + 2 * SZ_W);

  static bool attr_done = false;
  if (!attr_done) {
    hipFuncSetAttribute((const void*)k_gemm_qkv,
                        hipFuncAttributeMaxDynamicSharedMemorySize, 98304);
    hipFuncSetAttribute((const void*)k_gemm_out,
                        hipFuncAttributeMaxDynamicSharedMemorySize, 98304);
    attr_done = true;
  }

  k_cvt4<<<2048, 256, 0, stream>>>(x, wq, wk, wv, xb, wqb, wkb, wvb);

  k_gemm_qkv<<<dim3(24, 32), 512, 98304, stream>>>(xb, wqb, wkb, wvb, bq, bk,
                                                   bv, qb, kb, vtb);
  k_cvt<<<1024, 256, 0, stream>>>(wo, wqb, (DMODEL * DMODEL) / 8);

  k_norm_rope<<<2 * MTOT, 256, 0, stream>>>(qb, kb, gq, gk, freqs);

  k_attn<<<512, 512, 0, stream>>>(qb, kb, vtb, xb);

  k_gemm_out<<<dim3(8, 32), 512, 98304, stream>>>(xb, wqb, bo, (float*)d_out);
}

// Round 4
// 301.950 us; speedup vs baseline: 1.1593x; 1.1593x over previous
//
#include <hip/hip_runtime.h>
#include <hip/hip_bf16.h>
#include <stdint.h>

// ---------------------------------------------------------------------------
// SelfAttention block: out = (attn(rope(rms(xWq)), rope(rms(xWk)), xWv)) Wo
// B=2, N=2048, D=2048, H=16, HD=128.  All GEMMs + attention in bf16 MFMA.
// ---------------------------------------------------------------------------

typedef __bf16 bf16;
typedef __bf16 bf16x8 __attribute__((ext_vector_type(8)));
typedef __bf16 bf16x4 __attribute__((ext_vector_type(4)));
typedef float  f32x4  __attribute__((ext_vector_type(4)));

#define MTOT   4096   // B*N token rows
#define DMODEL 2048
#define NSEQ   2048
#define NHEAD  16
#define HDIM   128

static __device__ __forceinline__ void async_ld16(const void* g, void* l) {
  void* gnc = const_cast<void*>(g);
  __builtin_amdgcn_global_load_lds((__attribute__((address_space(1))) void*)gnc,
                                   (__attribute__((address_space(3))) void*)l,
                                   16, 0, 0);
}

// ---------------------------------------------------------------------------
// Fused f32 -> bf16 converts: x, wq, wk, wv in one launch.
// ---------------------------------------------------------------------------
#define XG (MTOT * DMODEL / 8)      // 1048576 groups of 8
#define WG (DMODEL * DMODEL / 8)    // 524288

__global__ __launch_bounds__(256) void k_cvt4(
    const float* __restrict__ x, const float* __restrict__ wq,
    const float* __restrict__ wk, const float* __restrict__ wv,
    bf16* __restrict__ xb, bf16* __restrict__ wqb, bf16* __restrict__ wkb,
    bf16* __restrict__ wvb) {
  int stride = gridDim.x * blockDim.x;
  for (int i = blockIdx.x * blockDim.x + threadIdx.x; i < XG + 3 * WG;
       i += stride) {
    const float* src;
    bf16* dst;
    int off;
    if (i < XG) { src = x; dst = xb; off = i; }
    else if (i < XG + WG) { src = wq; dst = wqb; off = i - XG; }
    else if (i < XG + 2 * WG) { src = wk; dst = wkb; off = i - XG - WG; }
    else { src = wv; dst = wvb; off = i - XG - 2 * WG; }
    const float4* p = (const float4*)(src) + 2 * (size_t)off;
    float4 a = p[0], b = p[1];
    bf16x8 o;
    o[0] = (bf16)a.x; o[1] = (bf16)a.y; o[2] = (bf16)a.z; o[3] = (bf16)a.w;
    o[4] = (bf16)b.x; o[5] = (bf16)b.y; o[6] = (bf16)b.z; o[7] = (bf16)b.w;
    *((bf16x8*)(dst) + off) = o;
  }
}

__global__ __launch_bounds__(256) void k_cvt(const float* __restrict__ in,
                                             bf16* __restrict__ out, int n8) {
  int stride = gridDim.x * blockDim.x;
  for (int i = blockIdx.x * blockDim.x + threadIdx.x; i < n8; i += stride) {
    const float4* p = (const float4*)(in) + 2 * (size_t)i;
    float4 a = p[0], b = p[1];
    bf16x8 o;
    o[0] = (bf16)a.x; o[1] = (bf16)a.y; o[2] = (bf16)a.z; o[3] = (bf16)a.w;
    o[4] = (bf16)b.x; o[5] = (bf16)b.y; o[6] = (bf16)b.z; o[7] = (bf16)b.w;
    *((bf16x8*)(out) + i) = o;
  }
}

// ---------------------------------------------------------------------------
// GEMM v3: C[m][n] = sum_k A[m][k]*W[n][k] + bias[n].  128x256 tile, BK=64,
// 8 waves (2M x 4N), wave-tile 64x64.  Triple-buffered LDS (3 x 48KB),
// 2-deep prefetch: loads for tile kt+2 issued during iter kt; the ONLY
// VMEM wait is counted vmcnt(6) (tile kt+1's 6 loads land, kt+2's stay in
// flight).  RAW s_barrier everywhere -- __syncthreads() would re-drain
// vmcnt to 0 (the R3 regression).  2 phases/K-tile (k-slice split):
//   {8 ds_read + 3 stage-issue -> sched_barrier -> s_barrier ->
//    setprio(1) 16 MFMA setprio(0)}
// ds_read of phase p+1 overlaps sibling waves' MFMA of phase p.
// OUTMODE 0: bf16 row-major; 1: bf16 transposed (vt[b][n][s]); 2: f32.
// ---------------------------------------------------------------------------
#define BUFELEMS (384 * 64)   // 24576 bf16 = 48KB per buffer (A 128x64 + B 256x64)

template <int OUTMODE>
static __device__ __forceinline__ void gemm256_body(
    const bf16* __restrict__ A, const bf16* __restrict__ W,
    const float* __restrict__ bias, void* __restrict__ outp, int m0, int n0) {
  extern __shared__ __align__(16) bf16 dynls[];

  const int tid = threadIdx.x;
  const int lane = tid & 63, w = tid >> 6;
  const int wm = w >> 2, wn = w & 3;
  const int g = lane >> 4, r0 = lane & 15;

  f32x4 acc[4][4];
  const f32x4 vzero = {0.f, 0.f, 0.f, 0.f};
#pragma unroll
  for (int i = 0; i < 4; ++i)
#pragma unroll
    for (int j = 0; j < 4; ++j) acc[i][j] = vzero;

  const bf16* Abase = A + (size_t)m0 * DMODEL;
  const bf16* Wbase = W + (size_t)n0 * DMODEL;

  // stage halves: a = A chunks p0,p1 + B chunk p0 (3 loads); b = B p1..p3.
  auto stage_a = [&](int kt, int buf) {
    const bf16* asrc = Abase + kt * 64;
    const bf16* bsrc = Wbase + kt * 64;
    bf16* sBuf = dynls + buf * BUFELEMS;
#pragma unroll
    for (int p = 0; p < 2; ++p) {      // A: 128x64 = 1024 chunks
      int ch = tid + p * 512;
      int row = ch >> 3, c = (ch & 7) ^ (row & 7);
      async_ld16(asrc + (size_t)row * DMODEL + c * 8, sBuf + ch * 8);
    }
    {
      int ch = tid;                    // B chunks 0..511
      int row = ch >> 3, c = (ch & 7) ^ (row & 7);
      async_ld16(bsrc + (size_t)row * DMODEL + c * 8, sBuf + 128 * 64 + ch * 8);
    }
  };
  auto stage_b = [&](int kt, int buf) {
    const bf16* bsrc = Wbase + kt * 64;
    bf16* sBuf = dynls + buf * BUFELEMS + 128 * 64;
#pragma unroll
    for (int p = 1; p < 4; ++p) {      // B chunks 512..2047
      int ch = tid + p * 512;
      int row = ch >> 3, c = (ch & 7) ^ (row & 7);
      async_ld16(bsrc + (size_t)row * DMODEL + c * 8, sBuf + ch * 8);
    }
  };

  const int NT = DMODEL / 64;  // 32
  stage_a(0, 0); stage_b(0, 0);
  stage_a(1, 1); stage_b(1, 1);                       // 12 in flight
  asm volatile("s_waitcnt vmcnt(6)" ::: "memory");    // tile 0 landed
  __builtin_amdgcn_s_barrier();

  for (int kt = 0; kt < NT; ++kt) {
    const bf16* sA = dynls + (kt % 3) * BUFELEMS;
    const bf16* sB = sA + 128 * 64;
    const bool pf = (kt + 2) < NT;
    const int nb = (kt + 2) % 3;

#pragma unroll
    for (int ks = 0; ks < 2; ++ks) {
      bf16x8 af[4], bfr[4];
      const int cc = ks * 4 + g;
#pragma unroll
      for (int i = 0; i < 4; ++i) {
        int ra = wm * 64 + i * 16 + r0;
        af[i] = *(const bf16x8*)(sA + ra * 64 + ((cc ^ (ra & 7)) << 3));
        int rb = wn * 64 + i * 16 + r0;
        bfr[i] = *(const bf16x8*)(sB + rb * 64 + ((cc ^ (rb & 7)) << 3));
      }
      if (ks == 0) {
        if (pf) stage_a(kt + 2, nb);
      } else {
        if (pf) {
          stage_b(kt + 2, nb);
          asm volatile("s_waitcnt vmcnt(6)" ::: "memory");  // kt+1 landed
        } else {
          asm volatile("s_waitcnt vmcnt(0)" ::: "memory");  // tail drain
        }
      }
      __builtin_amdgcn_sched_barrier(0);
      __builtin_amdgcn_s_barrier();
      __builtin_amdgcn_sched_barrier(0);
      __builtin_amdgcn_s_setprio(1);
#pragma unroll
      for (int i = 0; i < 4; ++i)
#pragma unroll
        for (int j = 0; j < 4; ++j)
          acc[i][j] = __builtin_amdgcn_mfma_f32_16x16x32_bf16(af[i], bfr[j],
                                                              acc[i][j], 0, 0, 0);
      __builtin_amdgcn_s_setprio(0);
    }
  }

  // epilogue: C frag layout col = lane&15, row = (lane>>4)*4 + r
#pragma unroll
  for (int i = 0; i < 4; ++i) {
#pragma unroll
    for (int j = 0; j < 4; ++j) {
      int mb = m0 + wm * 64 + i * 16 + g * 4;
      int n = n0 + wn * 64 + j * 16 + r0;
      float bn = bias[n];
      if (OUTMODE == 0) {
        bf16* o = (bf16*)outp;
#pragma unroll
        for (int r = 0; r < 4; ++r)
          o[(size_t)(mb + r) * DMODEL + n] = (bf16)(acc[i][j][r] + bn);
      } else if (OUTMODE == 2) {
        float* o = (float*)outp;
#pragma unroll
        for (int r = 0; r < 4; ++r)
          o[(size_t)(mb + r) * DMODEL + n] = acc[i][j][r] + bn;
      } else {
        bf16* o = (bf16*)outp;
        int bb = mb >> 11, s = mb & (NSEQ - 1);
        bf16x4 pk;
#pragma unroll
        for (int r = 0; r < 4; ++r) pk[r] = (bf16)(acc[i][j][r] + bn);
        *(bf16x4*)(o + (size_t)(bb * DMODEL + n) * NSEQ + s) = pk;
      }
    }
  }
}

__global__ __launch_bounds__(512, 2) void k_gemm_qkv(
    const bf16* __restrict__ xb, const bf16* __restrict__ wq,
    const bf16* __restrict__ wk, const bf16* __restrict__ wv,
    const float* __restrict__ bq, const float* __restrict__ bk,
    const float* __restrict__ bv, bf16* __restrict__ q, bf16* __restrict__ k,
    bf16* __restrict__ vt) {
  int nb = blockIdx.x;           // 24 = 3 sections x 8 n-blocks
  int m0 = blockIdx.y * 128;
  int sec = nb >> 3;
  int n0 = (nb & 7) * 256;
  if (sec == 0)
    gemm256_body<0>(xb, wq, bq, q, m0, n0);
  else if (sec == 1)
    gemm256_body<0>(xb, wk, bk, k, m0, n0);
  else
    gemm256_body<1>(xb, wv, bv, vt, m0, n0);
}

__global__ __launch_bounds__(512, 2) void k_gemm_out(
    const bf16* __restrict__ ab, const bf16* __restrict__ wo,
    const float* __restrict__ bo, float* __restrict__ out) {
  gemm256_body<2>(ab, wo, bo, out, blockIdx.y * 128, blockIdx.x * 256);
}

// ---------------------------------------------------------------------------
// Fused RMSNorm + RoPE (+ fold 1/sqrt(HD) into q so attn skips the scale).
// ---------------------------------------------------------------------------
__global__ __launch_bounds__(256) void k_norm_rope(
    bf16* __restrict__ q, bf16* __restrict__ kk, const float* __restrict__ gq,
    const float* __restrict__ gk, const float* __restrict__ freqs) {
  int bidx = blockIdx.x;
  bf16* buf = (bidx < MTOT) ? q : kk;
  const float* gw = (bidx < MTOT) ? gq : gk;
  float qs = (bidx < MTOT) ? 0.08838834764831845f : 1.0f;  // 1/sqrt(128)
  int row = bidx & (MTOT - 1);
  int s = row & (NSEQ - 1);
  int tid = threadIdx.x;
  int i0 = tid * 8;
  bf16* ptr = buf + (size_t)row * DMODEL + i0;
  bf16x8 v = *(const bf16x8*)ptr;
  float x[8];
  float ssq = 0.f;
#pragma unroll
  for (int j = 0; j < 8; ++j) {
    x[j] = (float)v[j];
    ssq += x[j] * x[j];
  }
#pragma unroll
  for (int off = 1; off < 64; off <<= 1) ssq += __shfl_xor(ssq, off);
  __shared__ float part[4];
  if ((tid & 63) == 0) part[tid >> 6] = ssq;
  __syncthreads();
  float tot = part[0] + part[1] + part[2] + part[3];
  float sc = rsqrtf(tot * (1.f / DMODEL) + 1e-6f) * qs;
  float4 g0 = *(const float4*)(gw + i0);
  float4 g1 = *(const float4*)(gw + i0 + 4);
  float y[8];
  y[0] = x[0] * sc * g0.x; y[1] = x[1] * sc * g0.y;
  y[2] = x[2] * sc * g0.z; y[3] = x[3] * sc * g0.w;
  y[4] = x[4] * sc * g1.x; y[5] = x[5] * sc * g1.y;
  y[6] = x[6] * sc * g1.z; y[7] = x[7] * sc * g1.w;
  int dl = i0 & (HDIM - 1);
  const float* fp = freqs + (size_t)s * HDIM + dl;
  float4 f0 = *(const float4*)fp;
  float4 f1 = *(const float4*)(fp + 4);
  bf16x8 out;
  out[0] = (bf16)(y[0] * f0.x - y[1] * f0.y);
  out[1] = (bf16)(y[0] * f0.y + y[1] * f0.x);
  out[2] = (bf16)(y[2] * f0.z - y[3] * f0.w);
  out[3] = (bf16)(y[2] * f0.w + y[3] * f0.z);
  out[4] = (bf16)(y[4] * f1.x - y[5] * f1.y);
  out[5] = (bf16)(y[4] * f1.y + y[5] * f1.x);
  out[6] = (bf16)(y[6] * f1.z - y[7] * f1.w);
  out[7] = (bf16)(y[6] * f1.w + y[7] * f1.z);
  *(bf16x8*)ptr = out;
}

// ---------------------------------------------------------------------------
// Flash attention v2 (unchanged from R2): swapped QK^T, in-register softmax,
// P via cvt_pk + shfl, K/V double-buffer prefetch.
// ---------------------------------------------------------------------------
__global__ __launch_bounds__(512, 4) void k_attn(const bf16* __restrict__ q,
                                                 const bf16* __restrict__ k,
                                                 const bf16* __restrict__ vt,
                                                 bf16* __restrict__ o) {
  __shared__ __align__(16) bf16 sk[2][64 * 128];
  __shared__ __align__(16) bf16 sv[2][128 * 64];
  const int bid = blockIdx.x;
  const int idx = bid >> 3;
  const int bh = (bid & 7) * 4 + (idx >> 4);  // 4 bh per XCD
  const int qt = idx & 15;
  const int bb = bh >> 4, h = bh & 15;
  const int tid = threadIdx.x;
  const int lane = tid & 63, w = tid >> 6;
  const int g = lane >> 4, r0 = lane & 15;

  bf16x8 qf[4];
  {
    const bf16* qbase =
        q + (size_t)(bb * NSEQ + qt * 128 + w * 16 + r0) * DMODEL + h * HDIM;
#pragma unroll
    for (int ds = 0; ds < 4; ++ds)
      qf[ds] = *(const bf16x8*)(qbase + ds * 32 + g * 8);
  }
  f32x4 oacc[8];
  const f32x4 vzero = {0.f, 0.f, 0.f, 0.f};
#pragma unroll
  for (int dt = 0; dt < 8; ++dt) oacc[dt] = vzero;
  float m = -3.0e38f, l = 0.f;

  const bf16* kbase = k + (size_t)(bb * NSEQ) * DMODEL + h * HDIM;
  const bf16* vbase = vt + (size_t)(bb * DMODEL + h * HDIM) * NSEQ;

  const int s0lane = ((lane & 16) << 1) | r0;
  const int s1lane = s0lane | 16;
  const bool hi5 = (lane & 32) != 0;

  auto stage = [&](int t, int buf) {
    int k0 = t * 64;
#pragma unroll
    for (int p = 0; p < 2; ++p) {
      int ch = tid + p * 512;
      int row = ch >> 4, cs = ch & 15;
      int c = cs ^ (row & 7);
      async_ld16(kbase + (size_t)(k0 + row) * DMODEL + c * 8, &sk[buf][ch * 8]);
    }
#pragma unroll
    for (int p = 0; p < 2; ++p) {
      int ch = tid + p * 512;
      int row = ch >> 3, cs = ch & 7;
      int c = cs ^ (row & 7);
      async_ld16(vbase + (size_t)row * NSEQ + k0 + c * 8, &sv[buf][ch * 8]);
    }
  };

  stage(0, 0);
  for (int t = 0; t < NSEQ / 64; ++t) {
    const int cur = t & 1;
    asm volatile("s_waitcnt vmcnt(0)" ::: "memory");
    __syncthreads();
    if (t + 1 < NSEQ / 64) stage(t + 1, cur ^ 1);

    f32x4 sacc[4];
#pragma unroll
    for (int kkt = 0; kkt < 4; ++kkt) sacc[kkt] = vzero;
#pragma unroll
    for (int kkt = 0; kkt < 4; ++kkt) {
      int rk = kkt * 16 + r0;
#pragma unroll
      for (int ds = 0; ds < 4; ++ds) {
        int c = ds * 4 + g;
        bf16x8 kf = *(const bf16x8*)(&sk[cur][rk * 128 + ((c ^ (rk & 7)) << 3)]);
        sacc[kkt] =
            __builtin_amdgcn_mfma_f32_16x16x32_bf16(kf, qf[ds], sacc[kkt], 0, 0, 0);
      }
    }

    float pm = sacc[0][0];
#pragma unroll
    for (int kkt = 0; kkt < 4; ++kkt)
#pragma unroll
      for (int r = 0; r < 4; ++r) pm = fmaxf(pm, sacc[kkt][r]);
    pm = fmaxf(pm, __shfl_xor(pm, 16));
    pm = fmaxf(pm, __shfl_xor(pm, 32));
    const int need = __any(pm > m);
    const float mu = need ? fmaxf(m, pm) : m;

    uint32_t W[4][2];
    float rs = 0.f;
#pragma unroll
    for (int kkt = 0; kkt < 4; ++kkt) {
      float p0 = __expf(sacc[kkt][0] - mu);
      float p1 = __expf(sacc[kkt][1] - mu);
      float p2 = __expf(sacc[kkt][2] - mu);
      float p3 = __expf(sacc[kkt][3] - mu);
      rs += (p0 + p1) + (p2 + p3);
      asm("v_cvt_pk_bf16_f32 %0, %1, %2" : "=v"(W[kkt][0]) : "v"(p0), "v"(p1));
      asm("v_cvt_pk_bf16_f32 %0, %1, %2" : "=v"(W[kkt][1]) : "v"(p2), "v"(p3));
    }
    rs += __shfl_xor(rs, 16);
    rs += __shfl_xor(rs, 32);

    if (need) {
      float alpha = __expf(m - mu);
      m = mu;
      l = l * alpha + rs;
      float a4[4];
#pragma unroll
      for (int r = 0; r < 4; ++r)
        a4[r] = __shfl(alpha, (lane & 48) | (g * 4 + r));
#pragma unroll
      for (int dt = 0; dt < 8; ++dt)
#pragma unroll
        for (int r = 0; r < 4; ++r) oacc[dt][r] *= a4[r];
    } else {
      l += rs;
    }

#pragma unroll
    for (int ks = 0; ks < 2; ++ks) {
      union { uint32_t u[4]; bf16x8 v; } pa;
#pragma unroll
      for (int ww = 0; ww < 4; ++ww) {
        int src = (ww < 2) ? s0lane : s1lane;
        int lo = __shfl((int)W[2 * ks][ww & 1], src);
        int hv = __shfl((int)W[2 * ks + 1][ww & 1], src);
        pa.u[ww] = hi5 ? (uint32_t)hv : (uint32_t)lo;
      }
#pragma unroll
      for (int dt = 0; dt < 8; ++dt) {
        int rv = dt * 16 + r0;
        int c = ks * 4 + g;
        bf16x8 vf = *(const bf16x8*)(&sv[cur][rv * 64 + ((c ^ (rv & 7)) << 3)]);
        oacc[dt] =
            __builtin_amdgcn_mfma_f32_16x16x32_bf16(pa.v, vf, oacc[dt], 0, 0, 0);
      }
    }
  }

  float rl[4];
#pragma unroll
  for (int r = 0; r < 4; ++r) {
    float lr = __shfl(l, (lane & 48) | (g * 4 + r));
    rl[r] = 1.f / lr;
  }
  bf16* obase =
      o + (size_t)(bb * NSEQ + qt * 128 + w * 16 + g * 4) * DMODEL + h * HDIM;
#pragma unroll
  for (int dt = 0; dt < 8; ++dt)
#pragma unroll
    for (int r = 0; r < 4; ++r)
      obase[(size_t)r * DMODEL + dt * 16 + r0] = (bf16)(oacc[dt][r] * rl[r]);
}

// ---------------------------------------------------------------------------
extern "C" void kernel_launch(void* const* d_in, const int* in_sizes, int n_in,
                              void* d_out, int out_size, void* d_ws,
                              size_t ws_size, hipStream_t stream) {
  (void)in_sizes; (void)n_in; (void)out_size; (void)ws_size;
  const float* x = (const float*)d_in[0];
  const float* freqs = (const float*)d_in[1];
  const float* wq = (const float*)d_in[2];
  const float* bq = (const float*)d_in[3];
  const float* wk = (const float*)d_in[4];
  const float* bk = (const float*)d_in[5];
  const float* wv = (const float*)d_in[6];
  const float* bv = (const float*)d_in[7];
  const float* wo = (const float*)d_in[8];
  const float* bo = (const float*)d_in[9];
  const float* gq = (const float*)d_in[10];
  const float* gk = (const float*)d_in[11];

  char* ws = (char*)d_ws;
  const size_t SZ_TOK = (size_t)MTOT * DMODEL * sizeof(bf16);
  const size_t SZ_W = (size_t)DMODEL * DMODEL * sizeof(bf16);
  bf16* xb = (bf16*)ws;                 // attn-out after qkv
  bf16* qb = (bf16*)(ws + SZ_TOK);
  bf16* kb = (bf16*)(ws + 2 * SZ_TOK);
  bf16* vtb = (bf16*)(ws + 3 * SZ_TOK);
  bf16* wqb = (bf16*)(ws + 4 * SZ_TOK);  // wo-bf16 after qkv
  bf16* wkb = (bf16*)(ws + 4 * SZ_TOK + SZ_W);
  bf16* wvb = (bf16*)(ws + 4 * SZ_TOK + 2 * SZ_W);

  const int LDSB = 3 * BUFELEMS * (int)sizeof(bf16);  // 147456
  hipFuncSetAttribute((const void*)k_gemm_qkv,
                      hipFuncAttributeMaxDynamicSharedMemorySize, LDSB);
  hipFuncSetAttribute((const void*)k_gemm_out,
                      hipFuncAttributeMaxDynamicSharedMemorySize, LDSB);

  k_cvt4<<<2048, 256, 0, stream>>>(x, wq, wk, wv, xb, wqb, wkb, wvb);

  k_gemm_qkv<<<dim3(24, 32), 512, LDSB, stream>>>(xb, wqb, wkb, wvb, bq, bk,
                                                  bv, qb, kb, vtb);
  k_cvt<<<1024, 256, 0, stream>>>(wo, wqb, (DMODEL * DMODEL) / 8);

  k_norm_rope<<<2 * MTOT, 256, 0, stream>>>(qb, kb, gq, gk, freqs);

  k_attn<<<512, 512, 0, stream>>>(qb, kb, vtb, xb);

  k_gemm_out<<<dim3(8, 32), 512, LDSB, stream>>>(xb, wqb, bo, (float*)d_out);
}

// Round 6
// 270.249 us; speedup vs baseline: 1.2953x; 1.1173x over previous
//
#include <hip/hip_runtime.h>
#include <hip/hip_bf16.h>
#include <stdint.h>

// ---------------------------------------------------------------------------
// SelfAttention block: out = (attn(rope(rms(xWq)), rope(rms(xWk)), xWv)) Wo
// B=2, N=2048, D=2048, H=16, HD=128.  All GEMMs + attention in bf16 MFMA.
// ---------------------------------------------------------------------------

typedef __bf16 bf16;
typedef __bf16 bf16x8 __attribute__((ext_vector_type(8)));
typedef __bf16 bf16x4 __attribute__((ext_vector_type(4)));
typedef float  f32x4  __attribute__((ext_vector_type(4)));
typedef float  f32x16 __attribute__((ext_vector_type(16)));
typedef unsigned int uint2v __attribute__((ext_vector_type(2)));

#define MTOT   4096   // B*N token rows
#define DMODEL 2048
#define NSEQ   2048
#define NHEAD  16
#define HDIM   128

static __device__ __forceinline__ void async_ld16(const void* g, void* l) {
  void* gnc = const_cast<void*>(g);
  __builtin_amdgcn_global_load_lds((__attribute__((address_space(1))) void*)gnc,
                                   (__attribute__((address_space(3))) void*)l,
                                   16, 0, 0);
}

// ---------------------------------------------------------------------------
// Fused f32 -> bf16 converts: x, wq, wk, wv in one launch.
// ---------------------------------------------------------------------------
#define XG (MTOT * DMODEL / 8)      // 1048576 groups of 8
#define WG (DMODEL * DMODEL / 8)    // 524288

__global__ __launch_bounds__(256) void k_cvt4(
    const float* __restrict__ x, const float* __restrict__ wq,
    const float* __restrict__ wk, const float* __restrict__ wv,
    bf16* __restrict__ xb, bf16* __restrict__ wqb, bf16* __restrict__ wkb,
    bf16* __restrict__ wvb) {
  int stride = gridDim.x * blockDim.x;
  for (int i = blockIdx.x * blockDim.x + threadIdx.x; i < XG + 3 * WG;
       i += stride) {
    const float* src;
    bf16* dst;
    int off;
    if (i < XG) { src = x; dst = xb; off = i; }
    else if (i < XG + WG) { src = wq; dst = wqb; off = i - XG; }
    else if (i < XG + 2 * WG) { src = wk; dst = wkb; off = i - XG - WG; }
    else { src = wv; dst = wvb; off = i - XG - 2 * WG; }
    const float4* p = (const float4*)(src) + 2 * (size_t)off;
    float4 a = p[0], b = p[1];
    bf16x8 o;
    o[0] = (bf16)a.x; o[1] = (bf16)a.y; o[2] = (bf16)a.z; o[3] = (bf16)a.w;
    o[4] = (bf16)b.x; o[5] = (bf16)b.y; o[6] = (bf16)b.z; o[7] = (bf16)b.w;
    *((bf16x8*)(dst) + off) = o;
  }
}

__global__ __launch_bounds__(256) void k_cvt(const float* __restrict__ in,
                                             bf16* __restrict__ out, int n8) {
  int stride = gridDim.x * blockDim.x;
  for (int i = blockIdx.x * blockDim.x + threadIdx.x; i < n8; i += stride) {
    const float4* p = (const float4*)(in) + 2 * (size_t)i;
    float4 a = p[0], b = p[1];
    bf16x8 o;
    o[0] = (bf16)a.x; o[1] = (bf16)a.y; o[2] = (bf16)a.z; o[3] = (bf16)a.w;
    o[4] = (bf16)b.x; o[5] = (bf16)b.y; o[6] = (bf16)b.z; o[7] = (bf16)b.w;
    *((bf16x8*)(out) + i) = o;
  }
}

// ---------------------------------------------------------------------------
// GEMM v3 (unchanged from R4): 128x256 tile, BK=64, 8 waves, triple-buffered
// LDS, counted vmcnt(6), raw s_barrier.
// ---------------------------------------------------------------------------
#define BUFELEMS (384 * 64)   // 48KB per buffer (A 128x64 + B 256x64)

template <int OUTMODE>
static __device__ __forceinline__ void gemm256_body(
    const bf16* __restrict__ A, const bf16* __restrict__ W,
    const float* __restrict__ bias, void* __restrict__ outp, int m0, int n0) {
  extern __shared__ __align__(16) bf16 dynls[];

  const int tid = threadIdx.x;
  const int lane = tid & 63, w = tid >> 6;
  const int wm = w >> 2, wn = w & 3;
  const int g = lane >> 4, r0 = lane & 15;

  f32x4 acc[4][4];
  const f32x4 vzero = {0.f, 0.f, 0.f, 0.f};
#pragma unroll
  for (int i = 0; i < 4; ++i)
#pragma unroll
    for (int j = 0; j < 4; ++j) acc[i][j] = vzero;

  const bf16* Abase = A + (size_t)m0 * DMODEL;
  const bf16* Wbase = W + (size_t)n0 * DMODEL;

  auto stage_a = [&](int kt, int buf) {
    const bf16* asrc = Abase + kt * 64;
    const bf16* bsrc = Wbase + kt * 64;
    bf16* sBuf = dynls + buf * BUFELEMS;
#pragma unroll
    for (int p = 0; p < 2; ++p) {
      int ch = tid + p * 512;
      int row = ch >> 3, c = (ch & 7) ^ (row & 7);
      async_ld16(asrc + (size_t)row * DMODEL + c * 8, sBuf + ch * 8);
    }
    {
      int ch = tid;
      int row = ch >> 3, c = (ch & 7) ^ (row & 7);
      async_ld16(bsrc + (size_t)row * DMODEL + c * 8, sBuf + 128 * 64 + ch * 8);
    }
  };
  auto stage_b = [&](int kt, int buf) {
    const bf16* bsrc = Wbase + kt * 64;
    bf16* sBuf = dynls + buf * BUFELEMS + 128 * 64;
#pragma unroll
    for (int p = 1; p < 4; ++p) {
      int ch = tid + p * 512;
      int row = ch >> 3, c = (ch & 7) ^ (row & 7);
      async_ld16(bsrc + (size_t)row * DMODEL + c * 8, sBuf + ch * 8);
    }
  };

  const int NT = DMODEL / 64;  // 32
  stage_a(0, 0); stage_b(0, 0);
  stage_a(1, 1); stage_b(1, 1);
  asm volatile("s_waitcnt vmcnt(6)" ::: "memory");
  __builtin_amdgcn_s_barrier();

  for (int kt = 0; kt < NT; ++kt) {
    const bf16* sA = dynls + (kt % 3) * BUFELEMS;
    const bf16* sB = sA + 128 * 64;
    const bool pf = (kt + 2) < NT;
    const int nb = (kt + 2) % 3;

#pragma unroll
    for (int ks = 0; ks < 2; ++ks) {
      bf16x8 af[4], bfr[4];
      const int cc = ks * 4 + g;
#pragma unroll
      for (int i = 0; i < 4; ++i) {
        int ra = wm * 64 + i * 16 + r0;
        af[i] = *(const bf16x8*)(sA + ra * 64 + ((cc ^ (ra & 7)) << 3));
        int rb = wn * 64 + i * 16 + r0;
        bfr[i] = *(const bf16x8*)(sB + rb * 64 + ((cc ^ (rb & 7)) << 3));
      }
      if (ks == 0) {
        if (pf) stage_a(kt + 2, nb);
      } else {
        if (pf) {
          stage_b(kt + 2, nb);
          asm volatile("s_waitcnt vmcnt(6)" ::: "memory");
        } else {
          asm volatile("s_waitcnt vmcnt(0)" ::: "memory");
        }
      }
      __builtin_amdgcn_sched_barrier(0);
      __builtin_amdgcn_s_barrier();
      __builtin_amdgcn_sched_barrier(0);
      __builtin_amdgcn_s_setprio(1);
#pragma unroll
      for (int i = 0; i < 4; ++i)
#pragma unroll
        for (int j = 0; j < 4; ++j)
          acc[i][j] = __builtin_amdgcn_mfma_f32_16x16x32_bf16(af[i], bfr[j],
                                                              acc[i][j], 0, 0, 0);
      __builtin_amdgcn_s_setprio(0);
    }
  }

#pragma unroll
  for (int i = 0; i < 4; ++i) {
#pragma unroll
    for (int j = 0; j < 4; ++j) {
      int mb = m0 + wm * 64 + i * 16 + g * 4;
      int n = n0 + wn * 64 + j * 16 + r0;
      float bn = bias[n];
      if (OUTMODE == 0) {
        bf16* o = (bf16*)outp;
#pragma unroll
        for (int r = 0; r < 4; ++r)
          o[(size_t)(mb + r) * DMODEL + n] = (bf16)(acc[i][j][r] + bn);
      } else if (OUTMODE == 2) {
        float* o = (float*)outp;
#pragma unroll
        for (int r = 0; r < 4; ++r)
          o[(size_t)(mb + r) * DMODEL + n] = acc[i][j][r] + bn;
      } else {
        bf16* o = (bf16*)outp;
        int bb = mb >> 11, s = mb & (NSEQ - 1);
        bf16x4 pk;
#pragma unroll
        for (int r = 0; r < 4; ++r) pk[r] = (bf16)(acc[i][j][r] + bn);
        *(bf16x4*)(o + (size_t)(bb * DMODEL + n) * NSEQ + s) = pk;
      }
    }
  }
}

__global__ __launch_bounds__(512, 2) void k_gemm_qkv(
    const bf16* __restrict__ xb, const bf16* __restrict__ wq,
    const bf16* __restrict__ wk, const bf16* __restrict__ wv,
    const float* __restrict__ bq, const float* __restrict__ bk,
    const float* __restrict__ bv, bf16* __restrict__ q, bf16* __restrict__ k,
    bf16* __restrict__ vt) {
  int nb = blockIdx.x;
  int m0 = blockIdx.y * 128;
  int sec = nb >> 3;
  int n0 = (nb & 7) * 256;
  if (sec == 0)
    gemm256_body<0>(xb, wq, bq, q, m0, n0);
  else if (sec == 1)
    gemm256_body<0>(xb, wk, bk, k, m0, n0);
  else
    gemm256_body<1>(xb, wv, bv, vt, m0, n0);
}

__global__ __launch_bounds__(512, 2) void k_gemm_out(
    const bf16* __restrict__ ab, const bf16* __restrict__ wo,
    const float* __restrict__ bo, float* __restrict__ out) {
  gemm256_body<2>(ab, wo, bo, out, blockIdx.y * 128, blockIdx.x * 256);
}

// ---------------------------------------------------------------------------
// Fused RMSNorm + RoPE (+ fold 1/sqrt(HD) into q so attn skips the scale).
// ---------------------------------------------------------------------------
__global__ __launch_bounds__(256) void k_norm_rope(
    bf16* __restrict__ q, bf16* __restrict__ kk, const float* __restrict__ gq,
    const float* __restrict__ gk, const float* __restrict__ freqs) {
  int bidx = blockIdx.x;
  bf16* buf = (bidx < MTOT) ? q : kk;
  const float* gw = (bidx < MTOT) ? gq : gk;
  float qs = (bidx < MTOT) ? 0.08838834764831845f : 1.0f;  // 1/sqrt(128)
  int row = bidx & (MTOT - 1);
  int s = row & (NSEQ - 1);
  int tid = threadIdx.x;
  int i0 = tid * 8;
  bf16* ptr = buf + (size_t)row * DMODEL + i0;
  bf16x8 v = *(const bf16x8*)ptr;
  float x[8];
  float ssq = 0.f;
#pragma unroll
  for (int j = 0; j < 8; ++j) {
    x[j] = (float)v[j];
    ssq += x[j] * x[j];
  }
#pragma unroll
  for (int off = 1; off < 64; off <<= 1) ssq += __shfl_xor(ssq, off);
  __shared__ float part[4];
  if ((tid & 63) == 0) part[tid >> 6] = ssq;
  __syncthreads();
  float tot = part[0] + part[1] + part[2] + part[3];
  float sc = rsqrtf(tot * (1.f / DMODEL) + 1e-6f) * qs;
  float4 g0 = *(const float4*)(gw + i0);
  float4 g1 = *(const float4*)(gw + i0 + 4);
  float y[8];
  y[0] = x[0] * sc * g0.x; y[1] = x[1] * sc * g0.y;
  y[2] = x[2] * sc * g0.z; y[3] = x[3] * sc * g0.w;
  y[4] = x[4] * sc * g1.x; y[5] = x[5] * sc * g1.y;
  y[6] = x[6] * sc * g1.z; y[7] = x[7] * sc * g1.w;
  int dl = i0 & (HDIM - 1);
  const float* fp = freqs + (size_t)s * HDIM + dl;
  float4 f0 = *(const float4*)fp;
  float4 f1 = *(const float4*)(fp + 4);
  bf16x8 out;
  out[0] = (bf16)(y[0] * f0.x - y[1] * f0.y);
  out[1] = (bf16)(y[0] * f0.y + y[1] * f0.x);
  out[2] = (bf16)(y[2] * f0.z - y[3] * f0.w);
  out[3] = (bf16)(y[2] * f0.w + y[3] * f0.z);
  out[4] = (bf16)(y[4] * f1.x - y[5] * f1.y);
  out[5] = (bf16)(y[4] * f1.y + y[5] * f1.x);
  out[6] = (bf16)(y[6] * f1.z - y[7] * f1.w);
  out[7] = (bf16)(y[6] * f1.w + y[7] * f1.z);
  *(bf16x8*)ptr = out;
}

// ---------------------------------------------------------------------------
// Flash attention v3b: 32x32x16 MFMA, both products swapped so q = lane&31
// is lane-local for softmax AND for the O-accumulator rescale.
//   S^T = K Q^T : sacc[s] reg r -> S[k=32s+(r&3)+8(r>>2)+4b5][q=l31]
//   O^T = V^T P^T : oacc[dt] reg r -> O[q=l31][d=32dt+(r&3)+8(r>>2)+4b5]
// P^T B-frags via cvt_pk + permlane32_swap.  permlane32_swap semantics
// (matching the HW-verified HK recipe): new_vdst = {vdst.lo, vsrc.lo},
// new_vsrc = {vdst.hi, vsrc.hi}; so swap(P2[4u], P2[4u+2]) gives lane-half
// b5=0 {own[4u], partner[4u]} and b5=1 {partner[4u+2], own[4u+2]} -> uniform
// uw = {ra.x, rb.x, ra.y, rb.y}.
// ---------------------------------------------------------------------------
__global__ __launch_bounds__(256, 2) void k_attn(const bf16* __restrict__ q,
                                                 const bf16* __restrict__ k,
                                                 const bf16* __restrict__ vt,
                                                 bf16* __restrict__ o) {
  __shared__ __align__(16) bf16 sk[2][64 * 128];
  __shared__ __align__(16) bf16 sv[2][128 * 64];
  const int bid = blockIdx.x;
  const int idx = bid >> 3;
  const int bh = (bid & 7) * 4 + (idx >> 4);  // 4 bh per XCD
  const int qt = idx & 15;
  const int bb = bh >> 4, h = bh & 15;
  const int tid = threadIdx.x;
  const int lane = tid & 63, w = tid >> 6;
  const int l31 = lane & 31, b5 = lane >> 5;

  // Q fragments (pre-scaled by 1/sqrt(HD)): qf[kk] = Q[q0+l31][16kk+8b5+j]
  bf16x8 qf[8];
  {
    const bf16* qb =
        q + (size_t)(bb * NSEQ + qt * 128 + w * 32 + l31) * DMODEL + h * HDIM +
        b5 * 8;
#pragma unroll
    for (int kk = 0; kk < 8; ++kk) qf[kk] = *(const bf16x8*)(qb + kk * 16);
  }

  f32x16 oacc[4];
#pragma unroll
  for (int dt = 0; dt < 4; ++dt)
#pragma unroll
    for (int r = 0; r < 16; ++r) oacc[dt][r] = 0.f;
  float m = -3.0e38f, l = 0.f;

  const bf16* kbase = k + (size_t)(bb * NSEQ) * DMODEL + h * HDIM;
  const bf16* vbase = vt + (size_t)(bb * DMODEL + h * HDIM) * NSEQ;

  auto stage = [&](int t, int buf) {
    int k0 = t * 64;
#pragma unroll
    for (int p = 0; p < 4; ++p) {  // K: 64 rows x 16 chunks
      int ch = tid + p * 256;
      int row = ch >> 4, cs = ch & 15;
      int c = cs ^ (row & 7);
      async_ld16(kbase + (size_t)(k0 + row) * DMODEL + c * 8, &sk[buf][ch * 8]);
    }
#pragma unroll
    for (int p = 0; p < 4; ++p) {  // V: 128 d-rows x 8 chunks
      int ch = tid + p * 256;
      int row = ch >> 3, cs = ch & 7;
      int c = cs ^ (row & 7);
      async_ld16(vbase + (size_t)row * NSEQ + k0 + c * 8, &sv[buf][ch * 8]);
    }
  };

  stage(0, 0);
  for (int t = 0; t < NSEQ / 64; ++t) {
    const int cur = t & 1;
    asm volatile("s_waitcnt vmcnt(0)" ::: "memory");
    __syncthreads();
    if (t + 1 < NSEQ / 64) stage(t + 1, cur ^ 1);  // overlaps compute

    // S^T = K Q^T
    f32x16 sacc[2];
#pragma unroll
    for (int s = 0; s < 2; ++s)
#pragma unroll
      for (int r = 0; r < 16; ++r) sacc[s][r] = 0.f;
#pragma unroll
    for (int s = 0; s < 2; ++s) {
      const int row = s * 32 + l31;
#pragma unroll
      for (int kk = 0; kk < 8; ++kk) {
        const int c = 2 * kk + b5;
        bf16x8 kf = *(const bf16x8*)(&sk[cur][row * 128 + ((c ^ (row & 7)) << 3)]);
        sacc[s] = __builtin_amdgcn_mfma_f32_32x32x16_bf16(kf, qf[kk], sacc[s],
                                                          0, 0, 0);
      }
    }

    // lane-local softmax for q = l31 (halves combined via permlane pair;
    // max/add over the pair is order-independent)
    float t1[8];
#pragma unroll
    for (int i = 0; i < 8; ++i)
      t1[i] = fmaxf(fmaxf(sacc[0][2 * i], sacc[0][2 * i + 1]),
                    fmaxf(sacc[1][2 * i], sacc[1][2 * i + 1]));
    float pm = fmaxf(fmaxf(fmaxf(t1[0], t1[1]), fmaxf(t1[2], t1[3])),
                     fmaxf(fmaxf(t1[4], t1[5]), fmaxf(t1[6], t1[7])));
    {
      uint2v r2 = __builtin_amdgcn_permlane32_swap(__float_as_uint(pm),
                                                   __float_as_uint(pm), false,
                                                   false);
      pm = fmaxf(__uint_as_float(r2.x), __uint_as_float(r2.y));
    }
    const int need = __any(pm > m + 8.0f);  // defer-max (T13)
    if (need) {
      float mn = fmaxf(m, pm);
      float alpha = __expf(m - mn);
      m = mn;
      l *= alpha;
#pragma unroll
      for (int dt = 0; dt < 4; ++dt)
#pragma unroll
        for (int r = 0; r < 16; ++r) oacc[dt][r] *= alpha;
    }

    // exp + row-sum
    float rs = 0.f;
#pragma unroll
    for (int s = 0; s < 2; ++s)
#pragma unroll
      for (int r = 0; r < 16; ++r) {
        float pv = __expf(sacc[s][r] - m);
        sacc[s][r] = pv;
        rs += pv;
      }
    {
      uint2v r2 = __builtin_amdgcn_permlane32_swap(__float_as_uint(rs),
                                                   __float_as_uint(rs), false,
                                                   false);
      rs = __uint_as_float(r2.x) + __uint_as_float(r2.y);
    }
    l += rs;

    // pack P to bf16 pairs: P2[s*8+i] = pk(p[2i], p[2i+1])
    uint32_t P2[16];
#pragma unroll
    for (int s = 0; s < 2; ++s)
#pragma unroll
      for (int i = 0; i < 8; ++i)
        asm("v_cvt_pk_bf16_f32 %0, %1, %2"
            : "=v"(P2[s * 8 + i])
            : "v"(sacc[s][2 * i]), "v"(sacc[s][2 * i + 1]));

    // O^T += V^T P^T ; per (s,u): pb words via 2 permlane32_swap
#pragma unroll
    for (int s = 0; s < 2; ++s) {
#pragma unroll
      for (int u = 0; u < 2; ++u) {
        union { uint32_t uw[4]; bf16x8 v; } pb;
        uint2v ra = __builtin_amdgcn_permlane32_swap(P2[s * 8 + 4 * u],
                                                     P2[s * 8 + 4 * u + 2],
                                                     false, false);
        uint2v rb = __builtin_amdgcn_permlane32_swap(P2[s * 8 + 4 * u + 1],
                                                     P2[s * 8 + 4 * u + 3],
                                                     false, false);
        pb.uw[0] = ra.x;
        pb.uw[1] = rb.x;
        pb.uw[2] = ra.y;
        pb.uw[3] = rb.y;
        const int c = 4 * s + 2 * u + b5;
#pragma unroll
        for (int dt = 0; dt < 4; ++dt) {
          const int rv = dt * 32 + l31;
          bf16x8 vf =
              *(const bf16x8*)(&sv[cur][rv * 64 + ((c ^ (rv & 7)) << 3)]);
          oacc[dt] = __builtin_amdgcn_mfma_f32_32x32x16_bf16(vf, pb.v, oacc[dt],
                                                             0, 0, 0);
        }
      }
    }
  }

  // epilogue: O[q=l31][d = 32dt + 8rg + 4b5 + e]
  const float rl = 1.f / l;
  bf16* ob = o + (size_t)(bb * NSEQ + qt * 128 + w * 32 + l31) * DMODEL +
             h * HDIM;
#pragma unroll
  for (int dt = 0; dt < 4; ++dt) {
#pragma unroll
    for (int rg = 0; rg < 4; ++rg) {
      bf16x4 pk4;
#pragma unroll
      for (int e = 0; e < 4; ++e) pk4[e] = (bf16)(oacc[dt][rg * 4 + e] * rl);
      *(bf16x4*)(ob + dt * 32 + rg * 8 + b5 * 4) = pk4;
    }
  }
}

// ---------------------------------------------------------------------------
extern "C" void kernel_launch(void* const* d_in, const int* in_sizes, int n_in,
                              void* d_out, int out_size, void* d_ws,
                              size_t ws_size, hipStream_t stream) {
  (void)in_sizes; (void)n_in; (void)out_size; (void)ws_size;
  const float* x = (const float*)d_in[0];
  const float* freqs = (const float*)d_in[1];
  const float* wq = (const float*)d_in[2];
  const float* bq = (const float*)d_in[3];
  const float* wk = (const float*)d_in[4];
  const float* bk = (const float*)d_in[5];
  const float* wv = (const float*)d_in[6];
  const float* bv = (const float*)d_in[7];
  const float* wo = (const float*)d_in[8];
  const float* bo = (const float*)d_in[9];
  const float* gq = (const float*)d_in[10];
  const float* gk = (const float*)d_in[11];

  char* ws = (char*)d_ws;
  const size_t SZ_TOK = (size_t)MTOT * DMODEL * sizeof(bf16);
  const size_t SZ_W = (size_t)DMODEL * DMODEL * sizeof(bf16);
  bf16* xb = (bf16*)ws;                 // attn-out after qkv
  bf16* qb = (bf16*)(ws + SZ_TOK);
  bf16* kb = (bf16*)(ws + 2 * SZ_TOK);
  bf16* vtb = (bf16*)(ws + 3 * SZ_TOK);
  bf16* wqb = (bf16*)(ws + 4 * SZ_TOK);  // wo-bf16 after qkv
  bf16* wkb = (bf16*)(ws + 4 * SZ_TOK + SZ_W);
  bf16* wvb = (bf16*)(ws + 4 * SZ_TOK + 2 * SZ_W);

  const int LDSB = 3 * BUFELEMS * (int)sizeof(bf16);  // 147456
  hipFuncSetAttribute((const void*)k_gemm_qkv,
                      hipFuncAttributeMaxDynamicSharedMemorySize, LDSB);
  hipFuncSetAttribute((const void*)k_gemm_out,
                      hipFuncAttributeMaxDynamicSharedMemorySize, LDSB);

  k_cvt4<<<2048, 256, 0, stream>>>(x, wq, wk, wv, xb, wqb, wkb, wvb);

  k_gemm_qkv<<<dim3(24, 32), 512, LDSB, stream>>>(xb, wqb, wkb, wvb, bq, bk,
                                                  bv, qb, kb, vtb);
  k_cvt<<<1024, 256, 0, stream>>>(wo, wqb, (DMODEL * DMODEL) / 8);

  k_norm_rope<<<2 * MTOT, 256, 0, stream>>>(qb, kb, gq, gk, freqs);

  k_attn<<<512, 256, 0, stream>>>(qb, kb, vtb, xb);

  k_gemm_out<<<dim3(8, 32), 512, LDSB, stream>>>(xb, wqb, bo, (float*)d_out);
}

// Round 7
// 263.270 us; speedup vs baseline: 1.3297x; 1.0265x over previous
//
#include <hip/hip_runtime.h>
#include <hip/hip_bf16.h>
#include <stdint.h>

// ---------------------------------------------------------------------------
// SelfAttention block: out = (attn(rope(rms(xWq)), rope(rms(xWk)), xWv)) Wo
// B=2, N=2048, D=2048, H=16, HD=128.  All GEMMs + attention in bf16 MFMA.
// ---------------------------------------------------------------------------

typedef __bf16 bf16;
typedef __bf16 bf16x8 __attribute__((ext_vector_type(8)));
typedef __bf16 bf16x4 __attribute__((ext_vector_type(4)));
typedef float  f32x4  __attribute__((ext_vector_type(4)));
typedef float  f32x16 __attribute__((ext_vector_type(16)));
typedef unsigned int uint2v __attribute__((ext_vector_type(2)));

#define MTOT   4096   // B*N token rows
#define DMODEL 2048
#define NSEQ   2048
#define NHEAD  16
#define HDIM   128

static __device__ __forceinline__ void async_ld16(const void* g, void* l) {
  void* gnc = const_cast<void*>(g);
  __builtin_amdgcn_global_load_lds((__attribute__((address_space(1))) void*)gnc,
                                   (__attribute__((address_space(3))) void*)l,
                                   16, 0, 0);
}

// ---------------------------------------------------------------------------
// Fused f32 -> bf16 converts: x, wq, wk, wv in one launch.
// ---------------------------------------------------------------------------
#define XG (MTOT * DMODEL / 8)      // 1048576 groups of 8
#define WG (DMODEL * DMODEL / 8)    // 524288

__global__ __launch_bounds__(256) void k_cvt4(
    const float* __restrict__ x, const float* __restrict__ wq,
    const float* __restrict__ wk, const float* __restrict__ wv,
    bf16* __restrict__ xb, bf16* __restrict__ wqb, bf16* __restrict__ wkb,
    bf16* __restrict__ wvb) {
  int stride = gridDim.x * blockDim.x;
  for (int i = blockIdx.x * blockDim.x + threadIdx.x; i < XG + 3 * WG;
       i += stride) {
    const float* src;
    bf16* dst;
    int off;
    if (i < XG) { src = x; dst = xb; off = i; }
    else if (i < XG + WG) { src = wq; dst = wqb; off = i - XG; }
    else if (i < XG + 2 * WG) { src = wk; dst = wkb; off = i - XG - WG; }
    else { src = wv; dst = wvb; off = i - XG - 2 * WG; }
    const float4* p = (const float4*)(src) + 2 * (size_t)off;
    float4 a = p[0], b = p[1];
    bf16x8 o;
    o[0] = (bf16)a.x; o[1] = (bf16)a.y; o[2] = (bf16)a.z; o[3] = (bf16)a.w;
    o[4] = (bf16)b.x; o[5] = (bf16)b.y; o[6] = (bf16)b.z; o[7] = (bf16)b.w;
    *((bf16x8*)(dst) + off) = o;
  }
}

__global__ __launch_bounds__(256) void k_cvt(const float* __restrict__ in,
                                             bf16* __restrict__ out, int n8) {
  int stride = gridDim.x * blockDim.x;
  for (int i = blockIdx.x * blockDim.x + threadIdx.x; i < n8; i += stride) {
    const float4* p = (const float4*)(in) + 2 * (size_t)i;
    float4 a = p[0], b = p[1];
    bf16x8 o;
    o[0] = (bf16)a.x; o[1] = (bf16)a.y; o[2] = (bf16)a.z; o[3] = (bf16)a.w;
    o[4] = (bf16)b.x; o[5] = (bf16)b.y; o[6] = (bf16)b.z; o[7] = (bf16)b.w;
    *((bf16x8*)(out) + i) = o;
  }
}

// ---------------------------------------------------------------------------
// GEMM qk: 256x256 tile, BK=64, 8 waves (2M x 4N), wave tile 128x64
// (8x4 16x16x32 frags, 128 acc VGPRs).  Double-buffered LDS 128KB, two raw
// s_barriers per K-tile, counted vmcnt(8) (next tile's 8 staging loads stay
// in flight through compute).  Quadrant phases Q(0,0),Q(0,1),Q(1,0),Q(1,1);
// a1-group reads issued during Q(0,*) so lgkm waits are covered.
// Handles BOTH q and k sections: grid 256 = 16 Mtiles x (8 q-N + 8 k-N).
// ---------------------------------------------------------------------------
__global__ __launch_bounds__(512, 2) void k_gemm_qk(
    const bf16* __restrict__ xb, const bf16* __restrict__ wq,
    const bf16* __restrict__ wk, const float* __restrict__ bq,
    const float* __restrict__ bk, bf16* __restrict__ q, bf16* __restrict__ k) {
  extern __shared__ __align__(16) bf16 dyn[];  // [2][A 16384 + B 16384]

  const int swz = (blockIdx.x & 7) * 32 + (blockIdx.x >> 3);  // XCD-grouped
  const int mt = swz >> 4, nt = swz & 15;
  const int sec = nt >> 3;
  const int m0 = mt * 256, n0 = (nt & 7) * 256;
  const bf16* W = sec ? wk : wq;
  const float* bias = sec ? bk : bq;
  bf16* outp = sec ? k : q;

  const int tid = threadIdx.x;
  const int lane = tid & 63, w = tid >> 6;
  const int wm = w >> 2, wn = w & 3;
  const int g = lane >> 4, r0 = lane & 15;

  f32x4 acc[8][4];
  const f32x4 vzero = {0.f, 0.f, 0.f, 0.f};
#pragma unroll
  for (int i = 0; i < 8; ++i)
#pragma unroll
    for (int j = 0; j < 4; ++j) acc[i][j] = vzero;

  const bf16* Abase = xb + (size_t)m0 * DMODEL;
  const bf16* Wbase = W + (size_t)n0 * DMODEL;

  auto stage = [&](int kt, int buf) {
    const bf16* asrc = Abase + kt * 64;
    const bf16* bsrc = Wbase + kt * 64;
    bf16* sA = dyn + buf * 32768;
    bf16* sB = sA + 16384;
#pragma unroll
    for (int p = 0; p < 4; ++p) {      // A: 256x64 = 2048 chunks
      int ch = tid + p * 512;
      int row = ch >> 3, c = (ch & 7) ^ (row & 7);
      async_ld16(asrc + (size_t)row * DMODEL + c * 8, sA + ch * 8);
    }
#pragma unroll
    for (int p = 0; p < 4; ++p) {      // B: 256x64
      int ch = tid + p * 512;
      int row = ch >> 3, c = (ch & 7) ^ (row & 7);
      async_ld16(bsrc + (size_t)row * DMODEL + c * 8, sB + ch * 8);
    }
  };

  const int NT = DMODEL / 64;  // 32
  stage(0, 0);
  for (int kt = 0; kt < NT; ++kt) {
    const int cur = kt & 1;
    if (kt > 0) __builtin_amdgcn_s_barrier();  // reads of buf cur^1 finished
    if (kt + 1 < NT) {
      stage(kt + 1, cur ^ 1);
      asm volatile("s_waitcnt vmcnt(8)" ::: "memory");  // tile kt landed
    } else {
      asm volatile("s_waitcnt vmcnt(0)" ::: "memory");
    }
    __builtin_amdgcn_s_barrier();              // buf cur visible to all
    const bf16* sA = dyn + cur * 32768;
    const bf16* sB = sA + 16384;

    bf16x8 a0[8], a1[8], b0[4], b1[4];
    // a0: A rows wm*128 + i*16 + r0 (i<4), 2 k-slices
#pragma unroll
    for (int i = 0; i < 4; ++i) {
      int ra = wm * 128 + i * 16 + r0;
#pragma unroll
      for (int ks = 0; ks < 2; ++ks) {
        int cc = ks * 4 + g;
        a0[i * 2 + ks] = *(const bf16x8*)(sA + ra * 64 + ((cc ^ (ra & 7)) << 3));
      }
    }
    // b0 / b1: B cols wn*64 + nq*32 + j*16 + r0
#pragma unroll
    for (int j = 0; j < 2; ++j) {
      int rb = wn * 64 + j * 16 + r0;
#pragma unroll
      for (int ks = 0; ks < 2; ++ks) {
        int cc = ks * 4 + g;
        b0[j * 2 + ks] = *(const bf16x8*)(sB + rb * 64 + ((cc ^ (rb & 7)) << 3));
      }
    }
#pragma unroll
    for (int j = 0; j < 2; ++j) {
      int rb = wn * 64 + 32 + j * 16 + r0;
#pragma unroll
      for (int ks = 0; ks < 2; ++ks) {
        int cc = ks * 4 + g;
        b1[j * 2 + ks] = *(const bf16x8*)(sB + rb * 64 + ((cc ^ (rb & 7)) << 3));
      }
    }
    // Q(0,0)
    __builtin_amdgcn_s_setprio(1);
#pragma unroll
    for (int i = 0; i < 4; ++i)
#pragma unroll
      for (int j = 0; j < 2; ++j)
#pragma unroll
        for (int ks = 0; ks < 2; ++ks)
          acc[i][j] = __builtin_amdgcn_mfma_f32_16x16x32_bf16(
              a0[i * 2 + ks], b0[j * 2 + ks], acc[i][j], 0, 0, 0);
    __builtin_amdgcn_s_setprio(0);
    // issue a1 reads (rows wm*128+64+...), overlap with Q(0,1)
#pragma unroll
    for (int i = 0; i < 4; ++i) {
      int ra = wm * 128 + 64 + i * 16 + r0;
#pragma unroll
      for (int ks = 0; ks < 2; ++ks) {
        int cc = ks * 4 + g;
        a1[i * 2 + ks] = *(const bf16x8*)(sA + ra * 64 + ((cc ^ (ra & 7)) << 3));
      }
    }
    // Q(0,1)
    __builtin_amdgcn_s_setprio(1);
#pragma unroll
    for (int i = 0; i < 4; ++i)
#pragma unroll
      for (int j = 0; j < 2; ++j)
#pragma unroll
        for (int ks = 0; ks < 2; ++ks)
          acc[i][2 + j] = __builtin_amdgcn_mfma_f32_16x16x32_bf16(
              a0[i * 2 + ks], b1[j * 2 + ks], acc[i][2 + j], 0, 0, 0);
    __builtin_amdgcn_s_setprio(0);
    // Q(1,0)
    __builtin_amdgcn_s_setprio(1);
#pragma unroll
    for (int i = 0; i < 4; ++i)
#pragma unroll
      for (int j = 0; j < 2; ++j)
#pragma unroll
        for (int ks = 0; ks < 2; ++ks)
          acc[4 + i][j] = __builtin_amdgcn_mfma_f32_16x16x32_bf16(
              a1[i * 2 + ks], b0[j * 2 + ks], acc[4 + i][j], 0, 0, 0);
    __builtin_amdgcn_s_setprio(0);
    // Q(1,1)
    __builtin_amdgcn_s_setprio(1);
#pragma unroll
    for (int i = 0; i < 4; ++i)
#pragma unroll
      for (int j = 0; j < 2; ++j)
#pragma unroll
        for (int ks = 0; ks < 2; ++ks)
          acc[4 + i][2 + j] = __builtin_amdgcn_mfma_f32_16x16x32_bf16(
              a1[i * 2 + ks], b1[j * 2 + ks], acc[4 + i][2 + j], 0, 0, 0);
    __builtin_amdgcn_s_setprio(0);
  }

  // epilogue: frag (i = mq*4+ii, j = nq*2+jj); C layout col=lane&15,
  // row=(lane>>4)*4+r within each 16x16 frag.
#pragma unroll
  for (int i = 0; i < 8; ++i) {
#pragma unroll
    for (int j = 0; j < 4; ++j) {
      int mb = m0 + wm * 128 + (i >> 2) * 64 + (i & 3) * 16 + g * 4;
      int n = n0 + wn * 64 + (j >> 1) * 32 + (j & 1) * 16 + r0;
      float bn = bias[n];
#pragma unroll
      for (int r = 0; r < 4; ++r)
        outp[(size_t)(mb + r) * DMODEL + n] = (bf16)(acc[i][j][r] + bn);
    }
  }
}

// ---------------------------------------------------------------------------
// GEMM v3 (R4 structure): 128x256 tile, triple-buffered LDS, counted
// vmcnt(6), raw s_barrier.  Used for the v-projection (transposed epilogue)
// and the output projection -- both exactly 256 blocks = 1 balanced round.
// ---------------------------------------------------------------------------
#define BUFELEMS (384 * 64)   // 48KB per buffer (A 128x64 + B 256x64)

template <int OUTMODE>
static __device__ __forceinline__ void gemm256_body(
    const bf16* __restrict__ A, const bf16* __restrict__ W,
    const float* __restrict__ bias, void* __restrict__ outp, int m0, int n0) {
  extern __shared__ __align__(16) bf16 dynls[];

  const int tid = threadIdx.x;
  const int lane = tid & 63, w = tid >> 6;
  const int wm = w >> 2, wn = w & 3;
  const int g = lane >> 4, r0 = lane & 15;

  f32x4 acc[4][4];
  const f32x4 vzero = {0.f, 0.f, 0.f, 0.f};
#pragma unroll
  for (int i = 0; i < 4; ++i)
#pragma unroll
    for (int j = 0; j < 4; ++j) acc[i][j] = vzero;

  const bf16* Abase = A + (size_t)m0 * DMODEL;
  const bf16* Wbase = W + (size_t)n0 * DMODEL;

  auto stage_a = [&](int kt, int buf) {
    const bf16* asrc = Abase + kt * 64;
    const bf16* bsrc = Wbase + kt * 64;
    bf16* sBuf = dynls + buf * BUFELEMS;
#pragma unroll
    for (int p = 0; p < 2; ++p) {
      int ch = tid + p * 512;
      int row = ch >> 3, c = (ch & 7) ^ (row & 7);
      async_ld16(asrc + (size_t)row * DMODEL + c * 8, sBuf + ch * 8);
    }
    {
      int ch = tid;
      int row = ch >> 3, c = (ch & 7) ^ (row & 7);
      async_ld16(bsrc + (size_t)row * DMODEL + c * 8, sBuf + 128 * 64 + ch * 8);
    }
  };
  auto stage_b = [&](int kt, int buf) {
    const bf16* bsrc = Wbase + kt * 64;
    bf16* sBuf = dynls + buf * BUFELEMS + 128 * 64;
#pragma unroll
    for (int p = 1; p < 4; ++p) {
      int ch = tid + p * 512;
      int row = ch >> 3, c = (ch & 7) ^ (row & 7);
      async_ld16(bsrc + (size_t)row * DMODEL + c * 8, sBuf + ch * 8);
    }
  };

  const int NT = DMODEL / 64;  // 32
  stage_a(0, 0); stage_b(0, 0);
  stage_a(1, 1); stage_b(1, 1);
  asm volatile("s_waitcnt vmcnt(6)" ::: "memory");
  __builtin_amdgcn_s_barrier();

  for (int kt = 0; kt < NT; ++kt) {
    const bf16* sA = dynls + (kt % 3) * BUFELEMS;
    const bf16* sB = sA + 128 * 64;
    const bool pf = (kt + 2) < NT;
    const int nb = (kt + 2) % 3;

#pragma unroll
    for (int ks = 0; ks < 2; ++ks) {
      bf16x8 af[4], bfr[4];
      const int cc = ks * 4 + g;
#pragma unroll
      for (int i = 0; i < 4; ++i) {
        int ra = wm * 64 + i * 16 + r0;
        af[i] = *(const bf16x8*)(sA + ra * 64 + ((cc ^ (ra & 7)) << 3));
        int rb = wn * 64 + i * 16 + r0;
        bfr[i] = *(const bf16x8*)(sB + rb * 64 + ((cc ^ (rb & 7)) << 3));
      }
      if (ks == 0) {
        if (pf) stage_a(kt + 2, nb);
      } else {
        if (pf) {
          stage_b(kt + 2, nb);
          asm volatile("s_waitcnt vmcnt(6)" ::: "memory");
        } else {
          asm volatile("s_waitcnt vmcnt(0)" ::: "memory");
        }
      }
      __builtin_amdgcn_sched_barrier(0);
      __builtin_amdgcn_s_barrier();
      __builtin_amdgcn_sched_barrier(0);
      __builtin_amdgcn_s_setprio(1);
#pragma unroll
      for (int i = 0; i < 4; ++i)
#pragma unroll
        for (int j = 0; j < 4; ++j)
          acc[i][j] = __builtin_amdgcn_mfma_f32_16x16x32_bf16(af[i], bfr[j],
                                                              acc[i][j], 0, 0, 0);
      __builtin_amdgcn_s_setprio(0);
    }
  }

#pragma unroll
  for (int i = 0; i < 4; ++i) {
#pragma unroll
    for (int j = 0; j < 4; ++j) {
      int mb = m0 + wm * 64 + i * 16 + g * 4;
      int n = n0 + wn * 64 + j * 16 + r0;
      float bn = bias[n];
      if (OUTMODE == 0) {
        bf16* o = (bf16*)outp;
#pragma unroll
        for (int r = 0; r < 4; ++r)
          o[(size_t)(mb + r) * DMODEL + n] = (bf16)(acc[i][j][r] + bn);
      } else if (OUTMODE == 2) {
        float* o = (float*)outp;
#pragma unroll
        for (int r = 0; r < 4; ++r)
          o[(size_t)(mb + r) * DMODEL + n] = acc[i][j][r] + bn;
      } else {
        bf16* o = (bf16*)outp;
        int bb = mb >> 11, s = mb & (NSEQ - 1);
        bf16x4 pk;
#pragma unroll
        for (int r = 0; r < 4; ++r) pk[r] = (bf16)(acc[i][j][r] + bn);
        *(bf16x4*)(o + (size_t)(bb * DMODEL + n) * NSEQ + s) = pk;
      }
    }
  }
}

__global__ __launch_bounds__(512, 2) void k_gemm_v(
    const bf16* __restrict__ xb, const bf16* __restrict__ wv,
    const float* __restrict__ bv, bf16* __restrict__ vt) {
  gemm256_body<1>(xb, wv, bv, vt, blockIdx.y * 128, blockIdx.x * 256);
}

__global__ __launch_bounds__(512, 2) void k_gemm_out(
    const bf16* __restrict__ ab, const bf16* __restrict__ wo,
    const float* __restrict__ bo, float* __restrict__ out) {
  gemm256_body<2>(ab, wo, bo, out, blockIdx.y * 128, blockIdx.x * 256);
}

// ---------------------------------------------------------------------------
// Fused RMSNorm + RoPE (+ fold 1/sqrt(HD) into q so attn skips the scale).
// ---------------------------------------------------------------------------
__global__ __launch_bounds__(256) void k_norm_rope(
    bf16* __restrict__ q, bf16* __restrict__ kk, const float* __restrict__ gq,
    const float* __restrict__ gk, const float* __restrict__ freqs) {
  int bidx = blockIdx.x;
  bf16* buf = (bidx < MTOT) ? q : kk;
  const float* gw = (bidx < MTOT) ? gq : gk;
  float qs = (bidx < MTOT) ? 0.08838834764831845f : 1.0f;  // 1/sqrt(128)
  int row = bidx & (MTOT - 1);
  int s = row & (NSEQ - 1);
  int tid = threadIdx.x;
  int i0 = tid * 8;
  bf16* ptr = buf + (size_t)row * DMODEL + i0;
  bf16x8 v = *(const bf16x8*)ptr;
  float x[8];
  float ssq = 0.f;
#pragma unroll
  for (int j = 0; j < 8; ++j) {
    x[j] = (float)v[j];
    ssq += x[j] * x[j];
  }
#pragma unroll
  for (int off = 1; off < 64; off <<= 1) ssq += __shfl_xor(ssq, off);
  __shared__ float part[4];
  if ((tid & 63) == 0) part[tid >> 6] = ssq;
  __syncthreads();
  float tot = part[0] + part[1] + part[2] + part[3];
  float sc = rsqrtf(tot * (1.f / DMODEL) + 1e-6f) * qs;
  float4 g0 = *(const float4*)(gw + i0);
  float4 g1 = *(const float4*)(gw + i0 + 4);
  float y[8];
  y[0] = x[0] * sc * g0.x; y[1] = x[1] * sc * g0.y;
  y[2] = x[2] * sc * g0.z; y[3] = x[3] * sc * g0.w;
  y[4] = x[4] * sc * g1.x; y[5] = x[5] * sc * g1.y;
  y[6] = x[6] * sc * g1.z; y[7] = x[7] * sc * g1.w;
  int dl = i0 & (HDIM - 1);
  const float* fp = freqs + (size_t)s * HDIM + dl;
  float4 f0 = *(const float4*)fp;
  float4 f1 = *(const float4*)(fp + 4);
  bf16x8 out;
  out[0] = (bf16)(y[0] * f0.x - y[1] * f0.y);
  out[1] = (bf16)(y[0] * f0.y + y[1] * f0.x);
  out[2] = (bf16)(y[2] * f0.z - y[3] * f0.w);
  out[3] = (bf16)(y[2] * f0.w + y[3] * f0.z);
  out[4] = (bf16)(y[4] * f1.x - y[5] * f1.y);
  out[5] = (bf16)(y[4] * f1.y + y[5] * f1.x);
  out[6] = (bf16)(y[6] * f1.z - y[7] * f1.w);
  out[7] = (bf16)(y[6] * f1.w + y[7] * f1.z);
  *(bf16x8*)ptr = out;
}

// ---------------------------------------------------------------------------
// Flash attention v3b (unchanged from R6): 32x32x16 MFMA, swapped products,
// lane-local softmax, permlane32_swap P-redistribution.
// ---------------------------------------------------------------------------
__global__ __launch_bounds__(256, 2) void k_attn(const bf16* __restrict__ q,
                                                 const bf16* __restrict__ k,
                                                 const bf16* __restrict__ vt,
                                                 bf16* __restrict__ o) {
  __shared__ __align__(16) bf16 sk[2][64 * 128];
  __shared__ __align__(16) bf16 sv[2][128 * 64];
  const int bid = blockIdx.x;
  const int idx = bid >> 3;
  const int bh = (bid & 7) * 4 + (idx >> 4);  // 4 bh per XCD
  const int qt = idx & 15;
  const int bb = bh >> 4, h = bh & 15;
  const int tid = threadIdx.x;
  const int lane = tid & 63, w = tid >> 6;
  const int l31 = lane & 31, b5 = lane >> 5;

  bf16x8 qf[8];
  {
    const bf16* qb =
        q + (size_t)(bb * NSEQ + qt * 128 + w * 32 + l31) * DMODEL + h * HDIM +
        b5 * 8;
#pragma unroll
    for (int kk = 0; kk < 8; ++kk) qf[kk] = *(const bf16x8*)(qb + kk * 16);
  }

  f32x16 oacc[4];
#pragma unroll
  for (int dt = 0; dt < 4; ++dt)
#pragma unroll
    for (int r = 0; r < 16; ++r) oacc[dt][r] = 0.f;
  float m = -3.0e38f, l = 0.f;

  const bf16* kbase = k + (size_t)(bb * NSEQ) * DMODEL + h * HDIM;
  const bf16* vbase = vt + (size_t)(bb * DMODEL + h * HDIM) * NSEQ;

  auto stage = [&](int t, int buf) {
    int k0 = t * 64;
#pragma unroll
    for (int p = 0; p < 4; ++p) {
      int ch = tid + p * 256;
      int row = ch >> 4, cs = ch & 15;
      int c = cs ^ (row & 7);
      async_ld16(kbase + (size_t)(k0 + row) * DMODEL + c * 8, &sk[buf][ch * 8]);
    }
#pragma unroll
    for (int p = 0; p < 4; ++p) {
      int ch = tid + p * 256;
      int row = ch >> 3, cs = ch & 7;
      int c = cs ^ (row & 7);
      async_ld16(vbase + (size_t)row * NSEQ + k0 + c * 8, &sv[buf][ch * 8]);
    }
  };

  stage(0, 0);
  for (int t = 0; t < NSEQ / 64; ++t) {
    const int cur = t & 1;
    asm volatile("s_waitcnt vmcnt(0)" ::: "memory");
    __syncthreads();
    if (t + 1 < NSEQ / 64) stage(t + 1, cur ^ 1);

    f32x16 sacc[2];
#pragma unroll
    for (int s = 0; s < 2; ++s)
#pragma unroll
      for (int r = 0; r < 16; ++r) sacc[s][r] = 0.f;
#pragma unroll
    for (int s = 0; s < 2; ++s) {
      const int row = s * 32 + l31;
#pragma unroll
      for (int kk = 0; kk < 8; ++kk) {
        const int c = 2 * kk + b5;
        bf16x8 kf = *(const bf16x8*)(&sk[cur][row * 128 + ((c ^ (row & 7)) << 3)]);
        sacc[s] = __builtin_amdgcn_mfma_f32_32x32x16_bf16(kf, qf[kk], sacc[s],
                                                          0, 0, 0);
      }
    }

    float t1[8];
#pragma unroll
    for (int i = 0; i < 8; ++i)
      t1[i] = fmaxf(fmaxf(sacc[0][2 * i], sacc[0][2 * i + 1]),
                    fmaxf(sacc[1][2 * i], sacc[1][2 * i + 1]));
    float pm = fmaxf(fmaxf(fmaxf(t1[0], t1[1]), fmaxf(t1[2], t1[3])),
                     fmaxf(fmaxf(t1[4], t1[5]), fmaxf(t1[6], t1[7])));
    {
      uint2v r2 = __builtin_amdgcn_permlane32_swap(__float_as_uint(pm),
                                                   __float_as_uint(pm), false,
                                                   false);
      pm = fmaxf(__uint_as_float(r2.x), __uint_as_float(r2.y));
    }
    const int need = __any(pm > m + 8.0f);  // defer-max (T13)
    if (need) {
      float mn = fmaxf(m, pm);
      float alpha = __expf(m - mn);
      m = mn;
      l *= alpha;
#pragma unroll
      for (int dt = 0; dt < 4; ++dt)
#pragma unroll
        for (int r = 0; r < 16; ++r) oacc[dt][r] *= alpha;
    }

    float rs = 0.f;
#pragma unroll
    for (int s = 0; s < 2; ++s)
#pragma unroll
      for (int r = 0; r < 16; ++r) {
        float pv = __expf(sacc[s][r] - m);
        sacc[s][r] = pv;
        rs += pv;
      }
    {
      uint2v r2 = __builtin_amdgcn_permlane32_swap(__float_as_uint(rs),
                                                   __float_as_uint(rs), false,
                                                   false);
      rs = __uint_as_float(r2.x) + __uint_as_float(r2.y);
    }
    l += rs;

    uint32_t P2[16];
#pragma unroll
    for (int s = 0; s < 2; ++s)
#pragma unroll
      for (int i = 0; i < 8; ++i)
        asm("v_cvt_pk_bf16_f32 %0, %1, %2"
            : "=v"(P2[s * 8 + i])
            : "v"(sacc[s][2 * i]), "v"(sacc[s][2 * i + 1]));

#pragma unroll
    for (int s = 0; s < 2; ++s) {
#pragma unroll
      for (int u = 0; u < 2; ++u) {
        union { uint32_t uw[4]; bf16x8 v; } pb;
        uint2v ra = __builtin_amdgcn_permlane32_swap(P2[s * 8 + 4 * u],
                                                     P2[s * 8 + 4 * u + 2],
                                                     false, false);
        uint2v rb = __builtin_amdgcn_permlane32_swap(P2[s * 8 + 4 * u + 1],
                                                     P2[s * 8 + 4 * u + 3],
                                                     false, false);
        pb.uw[0] = ra.x;
        pb.uw[1] = rb.x;
        pb.uw[2] = ra.y;
        pb.uw[3] = rb.y;
        const int c = 4 * s + 2 * u + b5;
#pragma unroll
        for (int dt = 0; dt < 4; ++dt) {
          const int rv = dt * 32 + l31;
          bf16x8 vf =
              *(const bf16x8*)(&sv[cur][rv * 64 + ((c ^ (rv & 7)) << 3)]);
          oacc[dt] = __builtin_amdgcn_mfma_f32_32x32x16_bf16(vf, pb.v, oacc[dt],
                                                             0, 0, 0);
        }
      }
    }
  }

  const float rl = 1.f / l;
  bf16* ob = o + (size_t)(bb * NSEQ + qt * 128 + w * 32 + l31) * DMODEL +
             h * HDIM;
#pragma unroll
  for (int dt = 0; dt < 4; ++dt) {
#pragma unroll
    for (int rg = 0; rg < 4; ++rg) {
      bf16x4 pk4;
#pragma unroll
      for (int e = 0; e < 4; ++e) pk4[e] = (bf16)(oacc[dt][rg * 4 + e] * rl);
      *(bf16x4*)(ob + dt * 32 + rg * 8 + b5 * 4) = pk4;
    }
  }
}

// ---------------------------------------------------------------------------
extern "C" void kernel_launch(void* const* d_in, const int* in_sizes, int n_in,
                              void* d_out, int out_size, void* d_ws,
                              size_t ws_size, hipStream_t stream) {
  (void)in_sizes; (void)n_in; (void)out_size; (void)ws_size;
  const float* x = (const float*)d_in[0];
  const float* freqs = (const float*)d_in[1];
  const float* wq = (const float*)d_in[2];
  const float* bq = (const float*)d_in[3];
  const float* wk = (const float*)d_in[4];
  const float* bk = (const float*)d_in[5];
  const float* wv = (const float*)d_in[6];
  const float* bv = (const float*)d_in[7];
  const float* wo = (const float*)d_in[8];
  const float* bo = (const float*)d_in[9];
  const float* gq = (const float*)d_in[10];
  const float* gk = (const float*)d_in[11];

  char* ws = (char*)d_ws;
  const size_t SZ_TOK = (size_t)MTOT * DMODEL * sizeof(bf16);
  const size_t SZ_W = (size_t)DMODEL * DMODEL * sizeof(bf16);
  bf16* xb = (bf16*)ws;                 // attn-out after qkv
  bf16* qb = (bf16*)(ws + SZ_TOK);
  bf16* kb = (bf16*)(ws + 2 * SZ_TOK);
  bf16* vtb = (bf16*)(ws + 3 * SZ_TOK);
  bf16* wqb = (bf16*)(ws + 4 * SZ_TOK);  // wo-bf16 after qk
  bf16* wkb = (bf16*)(ws + 4 * SZ_TOK + SZ_W);
  bf16* wvb = (bf16*)(ws + 4 * SZ_TOK + 2 * SZ_W);

  const int LDSB = 3 * BUFELEMS * (int)sizeof(bf16);  // 147456
  const int LDSQK = 2 * 32768 * (int)sizeof(bf16);    // 131072
  hipFuncSetAttribute((const void*)k_gemm_qk,
                      hipFuncAttributeMaxDynamicSharedMemorySize, LDSQK);
  hipFuncSetAttribute((const void*)k_gemm_v,
                      hipFuncAttributeMaxDynamicSharedMemorySize, LDSB);
  hipFuncSetAttribute((const void*)k_gemm_out,
                      hipFuncAttributeMaxDynamicSharedMemorySize, LDSB);

  k_cvt4<<<2048, 256, 0, stream>>>(x, wq, wk, wv, xb, wqb, wkb, wvb);

  k_gemm_qk<<<256, 512, LDSQK, stream>>>(xb, wqb, wkb, bq, bk, qb, kb);
  k_gemm_v<<<dim3(8, 32), 512, LDSB, stream>>>(xb, wvb, bv, vtb);

  k_cvt<<<1024, 256, 0, stream>>>(wo, wqb, (DMODEL * DMODEL) / 8);

  k_norm_rope<<<2 * MTOT, 256, 0, stream>>>(qb, kb, gq, gk, freqs);

  k_attn<<<512, 256, 0, stream>>>(qb, kb, vtb, xb);

  k_gemm_out<<<dim3(8, 32), 512, LDSB, stream>>>(xb, wqb, bo, (float*)d_out);
}